// Round 2
// baseline (716.983 us; speedup 1.0000x reference)
//
#include <hip/hip_runtime.h>
#include <hip/hip_bf16.h>
#include <math.h>

#define NT 8192
#define HD 768
#define ID 3072
#define NE 8
#define MAXB 136   // >= sum_e ceil(cnt_e/128) for sum cnt = 2*NT = 16384

typedef __bf16 bf16x8 __attribute__((ext_vector_type(8)));
typedef float f32x4 __attribute__((ext_vector_type(4)));

__device__ __forceinline__ unsigned short f2bf(float f) {
    union { float f; unsigned u; } v; v.f = f;
    unsigned r = v.u + 0x7FFFu + ((v.u >> 16) & 1u);   // RNE
    return (unsigned short)(r >> 16);
}

// global->LDS direct copy, 16B per lane. LDS dest is wave-uniform base + lane*16;
// global src is per-lane.
__device__ __forceinline__ void gload16(const void* g, void* l) {
    auto* lds = reinterpret_cast<__attribute__((address_space(3))) unsigned int*>(
        reinterpret_cast<uintptr_t>(l));
    auto* gp = reinterpret_cast<const __attribute__((address_space(1))) unsigned int*>(
        reinterpret_cast<uintptr_t>(g));
    __builtin_amdgcn_global_load_lds(gp, lds, 16, 0, 0);
}

__global__ void k_init(int* counts) {
    if (threadIdx.x < NE) counts[threadIdx.x] = 0;
}

__global__ void k_convertw(const float4* __restrict__ w1, const float4* __restrict__ w2,
                           ushort4* __restrict__ w1b, ushort4* __restrict__ w2b, int n) {
    int i = blockIdx.x * 256 + threadIdx.x;
    if (i >= n) return;
    float4 a = w1[i]; float4 b = w2[i];
    ushort4 ra, rb;
    ra.x = f2bf(a.x); ra.y = f2bf(a.y); ra.z = f2bf(a.z); ra.w = f2bf(a.w);
    rb.x = f2bf(b.x); rb.y = f2bf(b.y); rb.z = f2bf(b.z); rb.w = f2bf(b.w);
    w1b[i] = ra; w2b[i] = rb;
}

// Router: exact fp32 logits/softmax/top-2 (ties -> lowest index), append slots to
// per-expert lists, store gates, emit x in bf16.
__global__ void k_router(const float* __restrict__ x, const float* __restrict__ rw,
                         unsigned short* __restrict__ xb, float* __restrict__ gates,
                         int* __restrict__ lists, int* __restrict__ counts) {
    __shared__ float rws[NE * HD];
    const int tid = threadIdx.x;
    for (int i = tid; i < NE * HD; i += 256) rws[i] = rw[i];
    __syncthreads();
    const int wid = tid >> 6, lane = tid & 63;
    const int t = blockIdx.x * 4 + wid;
    const float* xp = x + (size_t)t * HD;
    float acc[NE];
#pragma unroll
    for (int e = 0; e < NE; e++) acc[e] = 0.f;
#pragma unroll
    for (int j = 0; j < HD / 64; j++) {
        float v = xp[lane + 64 * j];
        xb[(size_t)t * HD + lane + 64 * j] = f2bf(v);
#pragma unroll
        for (int e = 0; e < NE; e++) acc[e] += v * rws[e * HD + lane + 64 * j];
    }
#pragma unroll
    for (int e = 0; e < NE; e++)
        for (int off = 32; off; off >>= 1) acc[e] += __shfl_xor(acc[e], off);
    if (lane == 0) {
        float mx = acc[0];
#pragma unroll
        for (int e = 1; e < NE; e++) mx = fmaxf(mx, acc[e]);
        float p[NE], s = 0.f;
#pragma unroll
        for (int e = 0; e < NE; e++) { p[e] = __expf(acc[e] - mx); s += p[e]; }
        float inv = 1.f / s;
        int i1 = 0; float b1 = p[0];
#pragma unroll
        for (int e = 1; e < NE; e++) if (p[e] > b1) { b1 = p[e]; i1 = e; }
        int i2 = (i1 == 0) ? 1 : 0; float b2 = p[i2];
#pragma unroll
        for (int e = 0; e < NE; e++) if (e != i1 && p[e] > b2) { b2 = p[e]; i2 = e; }
        int pos0 = atomicAdd(&counts[i1], 1);
        lists[i1 * NT + pos0] = 2 * t;
        int pos1 = atomicAdd(&counts[i2], 1);
        lists[i2 * NT + pos1] = 2 * t + 1;
        gates[2 * t] = b1 * inv;
        gates[2 * t + 1] = b2 * inv;
    }
}

// Build compact block table: one entry per active 128-row m-tile -> (expert, m0).
__global__ void k_plan(const int* __restrict__ counts, int2* __restrict__ table) {
    if (threadIdx.x != 0) return;
    int b = 0;
    for (int e = 0; e < NE; e++) {
        int c = counts[e];
        for (int m0 = 0; m0 < c; m0 += 128) { table[b].x = e; table[b].y = m0; b++; }
    }
    for (; b < MAXB; b++) { table[b].x = -1; table[b].y = 0; }
}

// ---- shared GEMM body helpers -------------------------------------------
// LDS tile layout (k-major): phys 16B-chunk index = kchunk*128 + row,
// kchunk in [0,4) (8 bf16 each), row in [0,128). Staged via gload16 with the
// wave's linear 1024B dest window mapping to (kchunk = issue*2 + (wid>>1),
// row = (wid&1)*64 + lane) by construction of the per-lane global source.

// GEMM1: h[slot] = gelu(x_gathered @ w1[e]^T). 128x128 tile, BK=32, 4 waves,
// 2-phase LDS double buffer.
__launch_bounds__(256, 4)
__global__ void k_gemm1(const unsigned short* __restrict__ xb, const unsigned short* __restrict__ w1b,
                        const int* __restrict__ lists, const int* __restrict__ counts,
                        const int2* __restrict__ table,
                        unsigned short* __restrict__ hbuf) {
    const int2 ent = table[blockIdx.x];
    const int e = ent.x;
    if (e < 0) return;
    const int m0 = ent.y;
    const int cnt = counts[e];
    const int n0 = blockIdx.y * 128;
    __shared__ __align__(16) unsigned short As[2 * 4096];
    __shared__ __align__(16) unsigned short Bs[2 * 4096];
    __shared__ int slot_s[128];
    const int tid = threadIdx.x, lane = tid & 63, wid = tid >> 6;
    if (tid < 128) {
        int r = m0 + tid;
        slot_s[tid] = lists[e * NT + (r < cnt ? r : cnt - 1)];
    }
    __syncthreads();
    // staging source: this thread feeds (row lr, kchunks kc and kc+2)
    const int lr = (wid & 1) * 64 + lane;
    const int kc = (wid >> 1) * 8;                       // element offset of issue-0 chunk
    const int tokA = slot_s[lr] >> 1;
    const unsigned short* gA = xb + (size_t)tokA * HD + kc;
    const unsigned short* gB = w1b + ((size_t)(e * ID + n0 + lr)) * HD + kc;
    unsigned short* lA0 = As + wid * 512;                // bytes: wid*1024
    unsigned short* lB0 = Bs + wid * 512;
    const int wr = wid >> 1, wc = wid & 1;
    f32x4 acc[4][4];
    f32x4 zero = {0.f, 0.f, 0.f, 0.f};
#pragma unroll
    for (int m = 0; m < 4; m++)
#pragma unroll
        for (int n = 0; n < 4; n++) acc[m][n] = zero;
    // prologue: stage tile 0 into buf 0
    gload16(gA, lA0); gload16(gA + 16, lA0 + 2048);
    gload16(gB, lB0); gload16(gB + 16, lB0 + 2048);
    gA += 32; gB += 32;
    __syncthreads();                                     // drains vmcnt(0)
    int cur = 0;
    for (int kt = 0; kt < HD / 32; ++kt) {
        if (kt + 1 < HD / 32) {
            int nx = cur ^ 1;
            gload16(gA, lA0 + nx * 4096); gload16(gA + 16, lA0 + nx * 4096 + 2048);
            gload16(gB, lB0 + nx * 4096); gload16(gB + 16, lB0 + nx * 4096 + 2048);
            gA += 32; gB += 32;
        }
        const bf16x8* pa = (const bf16x8*)(As + cur * 4096) + (lane >> 4) * 128 + wr * 64 + (lane & 15);
        const bf16x8* pb = (const bf16x8*)(Bs + cur * 4096) + (lane >> 4) * 128 + wc * 64 + (lane & 15);
        bf16x8 a[4], b[4];
#pragma unroll
        for (int m = 0; m < 4; m++) a[m] = pa[m * 16];
#pragma unroll
        for (int n = 0; n < 4; n++) b[n] = pb[n * 16];
#pragma unroll
        for (int m = 0; m < 4; m++)
#pragma unroll
            for (int n = 0; n < 4; n++)
                acc[m][n] = __builtin_amdgcn_mfma_f32_16x16x32_bf16(a[m], b[n], acc[m][n], 0, 0, 0);
        __syncthreads();                                 // drains vmcnt(0) incl. prefetch
        cur ^= 1;
    }
    const int rj = (lane >> 4) * 4, cn = lane & 15;
#pragma unroll
    for (int m = 0; m < 4; m++) {
#pragma unroll
        for (int j = 0; j < 4; j++) {
            int lr2 = wr * 64 + m * 16 + rj + j;
            if (m0 + lr2 < cnt) {
                int slot = slot_s[lr2];
                size_t rowoff = (size_t)slot * ID + n0 + wc * 64 + cn;
#pragma unroll
                for (int n = 0; n < 4; n++) {
                    float v = acc[m][n][j];
                    v = 0.5f * v * (1.f + erff(v * 0.70710678118654752f));  // exact gelu
                    hbuf[rowoff + n * 16] = f2bf(v);
                }
            }
        }
    }
}

// GEMM2: pout[slot] = gate[slot] * (h_gathered @ w2[e]^T). K=3072.
__launch_bounds__(256, 4)
__global__ void k_gemm2(const unsigned short* __restrict__ hbuf, const unsigned short* __restrict__ w2b,
                        const int* __restrict__ lists, const int* __restrict__ counts,
                        const int2* __restrict__ table,
                        const float* __restrict__ gates, float* __restrict__ pout) {
    const int2 ent = table[blockIdx.x];
    const int e = ent.x;
    if (e < 0) return;
    const int m0 = ent.y;
    const int cnt = counts[e];
    const int n0 = blockIdx.y * 128;
    __shared__ __align__(16) unsigned short As[2 * 4096];
    __shared__ __align__(16) unsigned short Bs[2 * 4096];
    __shared__ int slot_s[128];
    const int tid = threadIdx.x, lane = tid & 63, wid = tid >> 6;
    if (tid < 128) {
        int r = m0 + tid;
        slot_s[tid] = lists[e * NT + (r < cnt ? r : cnt - 1)];
    }
    __syncthreads();
    const int lr = (wid & 1) * 64 + lane;
    const int kc = (wid >> 1) * 8;
    const unsigned short* gA = hbuf + (size_t)slot_s[lr] * ID + kc;
    const unsigned short* gB = w2b + ((size_t)(e * HD + n0 + lr)) * ID + kc;
    unsigned short* lA0 = As + wid * 512;
    unsigned short* lB0 = Bs + wid * 512;
    const int wr = wid >> 1, wc = wid & 1;
    f32x4 acc[4][4];
    f32x4 zero = {0.f, 0.f, 0.f, 0.f};
#pragma unroll
    for (int m = 0; m < 4; m++)
#pragma unroll
        for (int n = 0; n < 4; n++) acc[m][n] = zero;
    gload16(gA, lA0); gload16(gA + 16, lA0 + 2048);
    gload16(gB, lB0); gload16(gB + 16, lB0 + 2048);
    gA += 32; gB += 32;
    __syncthreads();
    int cur = 0;
    for (int kt = 0; kt < ID / 32; ++kt) {
        if (kt + 1 < ID / 32) {
            int nx = cur ^ 1;
            gload16(gA, lA0 + nx * 4096); gload16(gA + 16, lA0 + nx * 4096 + 2048);
            gload16(gB, lB0 + nx * 4096); gload16(gB + 16, lB0 + nx * 4096 + 2048);
            gA += 32; gB += 32;
        }
        const bf16x8* pa = (const bf16x8*)(As + cur * 4096) + (lane >> 4) * 128 + wr * 64 + (lane & 15);
        const bf16x8* pb = (const bf16x8*)(Bs + cur * 4096) + (lane >> 4) * 128 + wc * 64 + (lane & 15);
        bf16x8 a[4], b[4];
#pragma unroll
        for (int m = 0; m < 4; m++) a[m] = pa[m * 16];
#pragma unroll
        for (int n = 0; n < 4; n++) b[n] = pb[n * 16];
#pragma unroll
        for (int m = 0; m < 4; m++)
#pragma unroll
            for (int n = 0; n < 4; n++)
                acc[m][n] = __builtin_amdgcn_mfma_f32_16x16x32_bf16(a[m], b[n], acc[m][n], 0, 0, 0);
        __syncthreads();
        cur ^= 1;
    }
    const int rj = (lane >> 4) * 4, cn = lane & 15;
#pragma unroll
    for (int m = 0; m < 4; m++) {
#pragma unroll
        for (int j = 0; j < 4; j++) {
            int lr2 = wr * 64 + m * 16 + rj + j;
            if (m0 + lr2 < cnt) {
                int slot = slot_s[lr2];
                float g = gates[slot];
                size_t rowoff = (size_t)slot * HD + n0 + wc * 64 + cn;
#pragma unroll
                for (int n = 0; n < 4; n++)
                    pout[rowoff + n * 16] = g * acc[m][n][j];
            }
        }
    }
}

// out[t] = pout[2t] + pout[2t+1] + bias
__global__ void k_combine(const float4* __restrict__ pout, const float* __restrict__ bias,
                          float4* __restrict__ out) {
    int idx = blockIdx.x * 256 + threadIdx.x;   // over NT*HD/4
    int t = idx / (HD / 4);
    int c = idx - t * (HD / 4);
    float4 a = pout[(size_t)t * (2 * HD / 4) + c];
    float4 b = pout[(size_t)t * (2 * HD / 4) + HD / 4 + c];
    float4 bb = ((const float4*)bias)[c];
    float4 r;
    r.x = a.x + b.x + bb.x; r.y = a.y + b.y + bb.y;
    r.z = a.z + b.z + bb.z; r.w = a.w + b.w + bb.w;
    out[idx] = r;
}

extern "C" void kernel_launch(void* const* d_in, const int* in_sizes, int n_in,
                              void* d_out, int out_size, void* d_ws, size_t ws_size,
                              hipStream_t stream) {
    const float* x    = (const float*)d_in[0];
    const float* rw   = (const float*)d_in[1];
    const float* w1   = (const float*)d_in[2];
    const float* w2   = (const float*)d_in[3];
    const float* bias = (const float*)d_in[4];
    float* out = (float*)d_out;

    char* ws = (char*)d_ws;
    size_t off = 0;
    auto alloc = [&](size_t bytes) -> char* {
        char* p = ws + off;
        off += (bytes + 255) & ~(size_t)255;
        return p;
    };
    int*            counts = (int*)alloc(NE * 4);
    int2*           table  = (int2*)alloc(MAXB * sizeof(int2));
    int*            lists  = (int*)alloc((size_t)NE * NT * 4);
    float*          gates  = (float*)alloc((size_t)NT * 2 * 4);
    unsigned short* xb     = (unsigned short*)alloc((size_t)NT * HD * 2);
    unsigned short* w1b    = (unsigned short*)alloc((size_t)NE * ID * HD * 2);
    unsigned short* w2b    = (unsigned short*)alloc((size_t)NE * HD * ID * 2);
    unsigned short* hbuf   = (unsigned short*)alloc((size_t)NT * 2 * ID * 2);
    float*          pout   = (float*)alloc((size_t)NT * 2 * HD * 4);

    k_init<<<dim3(1), dim3(64), 0, stream>>>(counts);
    const int n4 = NE * ID * HD / 4;
    k_convertw<<<dim3((n4 + 255) / 256), dim3(256), 0, stream>>>(
        (const float4*)w1, (const float4*)w2, (ushort4*)w1b, (ushort4*)w2b, n4);
    k_router<<<dim3(NT / 4), dim3(256), 0, stream>>>(x, rw, xb, gates, lists, counts);
    k_plan<<<dim3(1), dim3(64), 0, stream>>>(counts, table);
    k_gemm1<<<dim3(MAXB, ID / 128), dim3(256), 0, stream>>>(xb, w1b, lists, counts, table, hbuf);
    k_gemm2<<<dim3(MAXB, HD / 128), dim3(256), 0, stream>>>(hbuf, w2b, lists, counts, table, gates, pout);
    k_combine<<<dim3(NT * HD / 4 / 256), dim3(256), 0, stream>>>((const float4*)pout, bias, (float4*)out);
}

// Round 3
// 679.420 us; speedup vs baseline: 1.0553x; 1.0553x over previous
//
#include <hip/hip_runtime.h>
#include <hip/hip_bf16.h>
#include <math.h>

#define NT 8192
#define HD 768
#define ID 3072
#define NE 8
#define MAXB 136   // >= sum_e ceil(cnt_e/128) for sum cnt = 2*NT = 16384

typedef __bf16 bf16x8 __attribute__((ext_vector_type(8)));
typedef float f32x4 __attribute__((ext_vector_type(4)));

__device__ __forceinline__ unsigned short f2bf(float f) {
    union { float f; unsigned u; } v; v.f = f;
    unsigned r = v.u + 0x7FFFu + ((v.u >> 16) & 1u);   // RNE
    return (unsigned short)(r >> 16);
}

// global->LDS direct copy, 16B per lane. LDS dest is wave-uniform base + lane*16;
// global src is per-lane.
__device__ __forceinline__ void gload16(const void* g, void* l) {
    auto* lds = reinterpret_cast<__attribute__((address_space(3))) unsigned int*>(
        reinterpret_cast<uintptr_t>(l));
    auto* gp = reinterpret_cast<const __attribute__((address_space(1))) unsigned int*>(
        reinterpret_cast<uintptr_t>(g));
    __builtin_amdgcn_global_load_lds(gp, lds, 16, 0, 0);
}

__global__ void k_init(int* counts) {
    if (threadIdx.x < NE) counts[threadIdx.x] = 0;
}

__global__ void k_convertw(const float4* __restrict__ w1, const float4* __restrict__ w2,
                           ushort4* __restrict__ w1b, ushort4* __restrict__ w2b, int n) {
    int i = blockIdx.x * 256 + threadIdx.x;
    if (i >= n) return;
    float4 a = w1[i]; float4 b = w2[i];
    ushort4 ra, rb;
    ra.x = f2bf(a.x); ra.y = f2bf(a.y); ra.z = f2bf(a.z); ra.w = f2bf(a.w);
    rb.x = f2bf(b.x); rb.y = f2bf(b.y); rb.z = f2bf(b.z); rb.w = f2bf(b.w);
    w1b[i] = ra; w2b[i] = rb;
}

// Router: exact fp32 logits/softmax/top-2 (ties -> lowest index), append slots to
// per-expert lists, store gates, emit x in bf16.
__global__ void k_router(const float* __restrict__ x, const float* __restrict__ rw,
                         unsigned short* __restrict__ xb, float* __restrict__ gates,
                         int* __restrict__ lists, int* __restrict__ counts) {
    __shared__ float rws[NE * HD];
    const int tid = threadIdx.x;
    for (int i = tid; i < NE * HD; i += 256) rws[i] = rw[i];
    __syncthreads();
    const int wid = tid >> 6, lane = tid & 63;
    const int t = blockIdx.x * 4 + wid;
    const float* xp = x + (size_t)t * HD;
    float acc[NE];
#pragma unroll
    for (int e = 0; e < NE; e++) acc[e] = 0.f;
#pragma unroll
    for (int j = 0; j < HD / 64; j++) {
        float v = xp[lane + 64 * j];
        xb[(size_t)t * HD + lane + 64 * j] = f2bf(v);
#pragma unroll
        for (int e = 0; e < NE; e++) acc[e] += v * rws[e * HD + lane + 64 * j];
    }
#pragma unroll
    for (int e = 0; e < NE; e++)
        for (int off = 32; off; off >>= 1) acc[e] += __shfl_xor(acc[e], off);
    if (lane == 0) {
        float mx = acc[0];
#pragma unroll
        for (int e = 1; e < NE; e++) mx = fmaxf(mx, acc[e]);
        float p[NE], s = 0.f;
#pragma unroll
        for (int e = 0; e < NE; e++) { p[e] = __expf(acc[e] - mx); s += p[e]; }
        float inv = 1.f / s;
        int i1 = 0; float b1 = p[0];
#pragma unroll
        for (int e = 1; e < NE; e++) if (p[e] > b1) { b1 = p[e]; i1 = e; }
        int i2 = (i1 == 0) ? 1 : 0; float b2 = p[i2];
#pragma unroll
        for (int e = 0; e < NE; e++) if (e != i1 && p[e] > b2) { b2 = p[e]; i2 = e; }
        int pos0 = atomicAdd(&counts[i1], 1);
        lists[i1 * NT + pos0] = 2 * t;
        int pos1 = atomicAdd(&counts[i2], 1);
        lists[i2 * NT + pos1] = 2 * t + 1;
        gates[2 * t] = b1 * inv;
        gates[2 * t + 1] = b2 * inv;
    }
}

// Compact block table: one entry per active 128-row m-tile -> (expert, m0). Parallel.
__global__ void k_plan(const int* __restrict__ counts, int2* __restrict__ table) {
    __shared__ int starts[NE + 1];
    const int tid = threadIdx.x;
    if (tid == 0) {
        int s = 0;
        for (int e = 0; e < NE; e++) { starts[e] = s; s += (counts[e] + 127) >> 7; }
        starts[NE] = s;
    }
    __syncthreads();
    for (int b = tid; b < MAXB; b += 256) {
        int e = -1, m0 = 0;
#pragma unroll
        for (int q = 0; q < NE; q++)
            if (b >= starts[q] && b < starts[q + 1]) { e = q; m0 = (b - starts[q]) << 7; }
        table[b].x = e; table[b].y = m0;
    }
}

// ---- GEMM bodies: 128x128 tile, BK=32, 4 waves, k-major LDS layout,
// 3-buffer pipeline with counted vmcnt (loads for t+1,t+2 always in flight).

// GEMM1: h[slot] = gelu(x_gathered @ w1[e]^T).
__launch_bounds__(256, 3)
__global__ void k_gemm1(const unsigned short* __restrict__ xb, const unsigned short* __restrict__ w1b,
                        const int* __restrict__ lists, const int* __restrict__ counts,
                        const int2* __restrict__ table,
                        unsigned short* __restrict__ hbuf) {
    const int2 ent = table[blockIdx.x];
    const int e = ent.x;
    if (e < 0) return;
    const int m0 = ent.y;
    const int cnt = counts[e];
    const int n0 = blockIdx.y * 128;
    __shared__ __align__(16) unsigned short As[3 * 4096];
    __shared__ __align__(16) unsigned short Bs[3 * 4096];
    __shared__ int slot_s[128];
    const int tid = threadIdx.x, lane = tid & 63, wid = tid >> 6;
    if (tid < 128) {
        int r = m0 + tid;
        slot_s[tid] = lists[e * NT + (r < cnt ? r : cnt - 1)];
    }
    __syncthreads();
    const int lr = (wid & 1) * 64 + lane;
    const int kc = (wid >> 1) * 8;
    const int tokA = slot_s[lr] >> 1;
    const unsigned short* gA = xb + (size_t)tokA * HD + kc;
    const unsigned short* gB = w1b + ((size_t)(e * ID + n0 + lr)) * HD + kc;
    const int wr = wid >> 1, wc = wid & 1;
    f32x4 acc[4][4];
    f32x4 zero = {0.f, 0.f, 0.f, 0.f};
#pragma unroll
    for (int m = 0; m < 4; m++)
#pragma unroll
        for (int n = 0; n < 4; n++) acc[m][n] = zero;

    const int NK = HD / 32;
    unsigned short* lA = As + wid * 512;
    unsigned short* lB = Bs + wid * 512;
    // prologue: tiles 0 and 1 into buffers 0 and 1
    gload16(gA, lA);          gload16(gA + 16, lA + 2048);
    gload16(gB, lB);          gload16(gB + 16, lB + 2048);
    gA += 32; gB += 32;
    gload16(gA, lA + 4096);   gload16(gA + 16, lA + 4096 + 2048);
    gload16(gB, lB + 4096);   gload16(gB + 16, lB + 4096 + 2048);
    gA += 32; gB += 32;
    for (int kt = 0; kt < NK; ++kt) {
        // retire tile kt's 4 loads (issued 2 iters ago), keep rest in flight
        if (kt == NK - 1) asm volatile("s_waitcnt vmcnt(0)\ns_barrier" ::: "memory");
        else              asm volatile("s_waitcnt vmcnt(4)\ns_barrier" ::: "memory");
        if (kt + 2 < NK) {
            int nb = (kt + 2) % 3;
            gload16(gA, lA + nb * 4096);      gload16(gA + 16, lA + nb * 4096 + 2048);
            gload16(gB, lB + nb * 4096);      gload16(gB + 16, lB + nb * 4096 + 2048);
            gA += 32; gB += 32;
        }
        const int cur = kt % 3;
        const bf16x8* pa = (const bf16x8*)(As + cur * 4096) + (lane >> 4) * 128 + wr * 64 + (lane & 15);
        const bf16x8* pb = (const bf16x8*)(Bs + cur * 4096) + (lane >> 4) * 128 + wc * 64 + (lane & 15);
        bf16x8 a[4], b[4];
#pragma unroll
        for (int m = 0; m < 4; m++) a[m] = pa[m * 16];
#pragma unroll
        for (int n = 0; n < 4; n++) b[n] = pb[n * 16];
#pragma unroll
        for (int m = 0; m < 4; m++)
#pragma unroll
            for (int n = 0; n < 4; n++)
                acc[m][n] = __builtin_amdgcn_mfma_f32_16x16x32_bf16(a[m], b[n], acc[m][n], 0, 0, 0);
    }
    const int rj = (lane >> 4) * 4, cn = lane & 15;
#pragma unroll
    for (int m = 0; m < 4; m++) {
#pragma unroll
        for (int j = 0; j < 4; j++) {
            int lr2 = wr * 64 + m * 16 + rj + j;
            if (m0 + lr2 < cnt) {
                int slot = slot_s[lr2];
                size_t rowoff = (size_t)slot * ID + n0 + wc * 64 + cn;
#pragma unroll
                for (int n = 0; n < 4; n++) {
                    float v = acc[m][n][j];
                    v = 0.5f * v * (1.f + erff(v * 0.70710678118654752f));  // exact gelu
                    hbuf[rowoff + n * 16] = f2bf(v);
                }
            }
        }
    }
}

// GEMM2: pout[slot] = gate[slot] * (h_gathered @ w2[e]^T). K=3072.
__launch_bounds__(256, 3)
__global__ void k_gemm2(const unsigned short* __restrict__ hbuf, const unsigned short* __restrict__ w2b,
                        const int* __restrict__ lists, const int* __restrict__ counts,
                        const int2* __restrict__ table,
                        const float* __restrict__ gates, float* __restrict__ pout) {
    const int2 ent = table[blockIdx.x];
    const int e = ent.x;
    if (e < 0) return;
    const int m0 = ent.y;
    const int cnt = counts[e];
    const int n0 = blockIdx.y * 128;
    __shared__ __align__(16) unsigned short As[3 * 4096];
    __shared__ __align__(16) unsigned short Bs[3 * 4096];
    __shared__ int slot_s[128];
    const int tid = threadIdx.x, lane = tid & 63, wid = tid >> 6;
    if (tid < 128) {
        int r = m0 + tid;
        slot_s[tid] = lists[e * NT + (r < cnt ? r : cnt - 1)];
    }
    __syncthreads();
    const int lr = (wid & 1) * 64 + lane;
    const int kc = (wid >> 1) * 8;
    const unsigned short* gA = hbuf + (size_t)slot_s[lr] * ID + kc;
    const unsigned short* gB = w2b + ((size_t)(e * HD + n0 + lr)) * ID + kc;
    const int wr = wid >> 1, wc = wid & 1;
    f32x4 acc[4][4];
    f32x4 zero = {0.f, 0.f, 0.f, 0.f};
#pragma unroll
    for (int m = 0; m < 4; m++)
#pragma unroll
        for (int n = 0; n < 4; n++) acc[m][n] = zero;

    const int NK = ID / 32;
    unsigned short* lA = As + wid * 512;
    unsigned short* lB = Bs + wid * 512;
    gload16(gA, lA);          gload16(gA + 16, lA + 2048);
    gload16(gB, lB);          gload16(gB + 16, lB + 2048);
    gA += 32; gB += 32;
    gload16(gA, lA + 4096);   gload16(gA + 16, lA + 4096 + 2048);
    gload16(gB, lB + 4096);   gload16(gB + 16, lB + 4096 + 2048);
    gA += 32; gB += 32;
    for (int kt = 0; kt < NK; ++kt) {
        if (kt == NK - 1) asm volatile("s_waitcnt vmcnt(0)\ns_barrier" ::: "memory");
        else              asm volatile("s_waitcnt vmcnt(4)\ns_barrier" ::: "memory");
        if (kt + 2 < NK) {
            int nb = (kt + 2) % 3;
            gload16(gA, lA + nb * 4096);      gload16(gA + 16, lA + nb * 4096 + 2048);
            gload16(gB, lB + nb * 4096);      gload16(gB + 16, lB + nb * 4096 + 2048);
            gA += 32; gB += 32;
        }
        const int cur = kt % 3;
        const bf16x8* pa = (const bf16x8*)(As + cur * 4096) + (lane >> 4) * 128 + wr * 64 + (lane & 15);
        const bf16x8* pb = (const bf16x8*)(Bs + cur * 4096) + (lane >> 4) * 128 + wc * 64 + (lane & 15);
        bf16x8 a[4], b[4];
#pragma unroll
        for (int m = 0; m < 4; m++) a[m] = pa[m * 16];
#pragma unroll
        for (int n = 0; n < 4; n++) b[n] = pb[n * 16];
#pragma unroll
        for (int m = 0; m < 4; m++)
#pragma unroll
            for (int n = 0; n < 4; n++)
                acc[m][n] = __builtin_amdgcn_mfma_f32_16x16x32_bf16(a[m], b[n], acc[m][n], 0, 0, 0);
    }
    const int rj = (lane >> 4) * 4, cn = lane & 15;
#pragma unroll
    for (int m = 0; m < 4; m++) {
#pragma unroll
        for (int j = 0; j < 4; j++) {
            int lr2 = wr * 64 + m * 16 + rj + j;
            if (m0 + lr2 < cnt) {
                int slot = slot_s[lr2];
                float g = gates[slot];
                size_t rowoff = (size_t)slot * HD + n0 + wc * 64 + cn;
#pragma unroll
                for (int n = 0; n < 4; n++)
                    pout[rowoff + n * 16] = g * acc[m][n][j];
            }
        }
    }
}

// out[t] = pout[2t] + pout[2t+1] + bias
__global__ void k_combine(const float4* __restrict__ pout, const float* __restrict__ bias,
                          float4* __restrict__ out) {
    int idx = blockIdx.x * 256 + threadIdx.x;   // over NT*HD/4
    int t = idx / (HD / 4);
    int c = idx - t * (HD / 4);
    float4 a = pout[(size_t)t * (2 * HD / 4) + c];
    float4 b = pout[(size_t)t * (2 * HD / 4) + HD / 4 + c];
    float4 bb = ((const float4*)bias)[c];
    float4 r;
    r.x = a.x + b.x + bb.x; r.y = a.y + b.y + bb.y;
    r.z = a.z + b.z + bb.z; r.w = a.w + b.w + bb.w;
    out[idx] = r;
}

extern "C" void kernel_launch(void* const* d_in, const int* in_sizes, int n_in,
                              void* d_out, int out_size, void* d_ws, size_t ws_size,
                              hipStream_t stream) {
    const float* x    = (const float*)d_in[0];
    const float* rw   = (const float*)d_in[1];
    const float* w1   = (const float*)d_in[2];
    const float* w2   = (const float*)d_in[3];
    const float* bias = (const float*)d_in[4];
    float* out = (float*)d_out;

    char* ws = (char*)d_ws;
    size_t off = 0;
    auto alloc = [&](size_t bytes) -> char* {
        char* p = ws + off;
        off += (bytes + 255) & ~(size_t)255;
        return p;
    };
    int*            counts = (int*)alloc(NE * 4);
    int2*           table  = (int2*)alloc(MAXB * sizeof(int2));
    int*            lists  = (int*)alloc((size_t)NE * NT * 4);
    float*          gates  = (float*)alloc((size_t)NT * 2 * 4);
    unsigned short* xb     = (unsigned short*)alloc((size_t)NT * HD * 2);
    unsigned short* w1b    = (unsigned short*)alloc((size_t)NE * ID * HD * 2);
    unsigned short* w2b    = (unsigned short*)alloc((size_t)NE * HD * ID * 2);
    unsigned short* hbuf   = (unsigned short*)alloc((size_t)NT * 2 * ID * 2);
    float*          pout   = (float*)alloc((size_t)NT * 2 * HD * 4);

    k_init<<<dim3(1), dim3(64), 0, stream>>>(counts);
    const int n4 = NE * ID * HD / 4;
    k_convertw<<<dim3((n4 + 255) / 256), dim3(256), 0, stream>>>(
        (const float4*)w1, (const float4*)w2, (ushort4*)w1b, (ushort4*)w2b, n4);
    k_router<<<dim3(NT / 4), dim3(256), 0, stream>>>(x, rw, xb, gates, lists, counts);
    k_plan<<<dim3(1), dim3(256), 0, stream>>>(counts, table);
    k_gemm1<<<dim3(MAXB, ID / 128), dim3(256), 0, stream>>>(xb, w1b, lists, counts, table, hbuf);
    k_gemm2<<<dim3(MAXB, HD / 128), dim3(256), 0, stream>>>(hbuf, w2b, lists, counts, table, gates, pout);
    k_combine<<<dim3(NT * HD / 4 / 256), dim3(256), 0, stream>>>((const float4*)pout, bias, (float4*)out);
}

// Round 4
// 487.824 us; speedup vs baseline: 1.4698x; 1.3928x over previous
//
#include <hip/hip_runtime.h>
#include <hip/hip_bf16.h>
#include <math.h>

#define NT 8192
#define HD 768
#define ID 3072
#define NE 8
#define BM 256
#define BN 128
#define BK 64
#define MAXB 72    // >= sum_e ceil(cnt_e/256), sum cnt = 16384
#define ASZ (BM * BK)   // shorts per A buffer (16384)
#define BSZ (BN * BK)   // shorts per B buffer (8192)

typedef __bf16 bf16x8 __attribute__((ext_vector_type(8)));
typedef float f32x4 __attribute__((ext_vector_type(4)));

__device__ __forceinline__ unsigned short f2bf(float f) {
    union { float f; unsigned u; } v; v.f = f;
    unsigned r = v.u + 0x7FFFu + ((v.u >> 16) & 1u);   // RNE
    return (unsigned short)(r >> 16);
}

// global->LDS direct copy, 16B/lane. LDS dest = wave-uniform base + lane*16.
__device__ __forceinline__ void gload16(const void* g, void* l) {
    auto* lds = reinterpret_cast<__attribute__((address_space(3))) unsigned int*>(
        reinterpret_cast<uintptr_t>(l));
    auto* gp = reinterpret_cast<const __attribute__((address_space(1))) unsigned int*>(
        reinterpret_cast<uintptr_t>(g));
    __builtin_amdgcn_global_load_lds(gp, lds, 16, 0, 0);
}

__global__ void k_init(int* counts) {
    if (threadIdx.x < NE) counts[threadIdx.x] = 0;
}

__global__ void k_convertw(const float4* __restrict__ w1, const float4* __restrict__ w2,
                           ushort4* __restrict__ w1b, ushort4* __restrict__ w2b, int n) {
    int i = blockIdx.x * 256 + threadIdx.x;
    if (i >= n) return;
    float4 a = w1[i]; float4 b = w2[i];
    ushort4 ra, rb;
    ra.x = f2bf(a.x); ra.y = f2bf(a.y); ra.z = f2bf(a.z); ra.w = f2bf(a.w);
    rb.x = f2bf(b.x); rb.y = f2bf(b.y); rb.z = f2bf(b.z); rb.w = f2bf(b.w);
    w1b[i] = ra; w2b[i] = rb;
}

// Router: exact fp32 logits/softmax/top-2 (ties -> lowest index), append slots to
// per-expert lists, store gates, emit x in bf16.
__global__ void k_router(const float* __restrict__ x, const float* __restrict__ rw,
                         unsigned short* __restrict__ xb, float* __restrict__ gates,
                         int* __restrict__ lists, int* __restrict__ counts) {
    __shared__ float rws[NE * HD];
    const int tid = threadIdx.x;
    for (int i = tid; i < NE * HD; i += 256) rws[i] = rw[i];
    __syncthreads();
    const int wid = tid >> 6, lane = tid & 63;
    const int t = blockIdx.x * 4 + wid;
    const float* xp = x + (size_t)t * HD;
    float acc[NE];
#pragma unroll
    for (int e = 0; e < NE; e++) acc[e] = 0.f;
#pragma unroll
    for (int j = 0; j < HD / 64; j++) {
        float v = xp[lane + 64 * j];
        xb[(size_t)t * HD + lane + 64 * j] = f2bf(v);
#pragma unroll
        for (int e = 0; e < NE; e++) acc[e] += v * rws[e * HD + lane + 64 * j];
    }
#pragma unroll
    for (int e = 0; e < NE; e++)
        for (int off = 32; off; off >>= 1) acc[e] += __shfl_xor(acc[e], off);
    if (lane == 0) {
        float mx = acc[0];
#pragma unroll
        for (int e = 1; e < NE; e++) mx = fmaxf(mx, acc[e]);
        float p[NE], s = 0.f;
#pragma unroll
        for (int e = 0; e < NE; e++) { p[e] = __expf(acc[e] - mx); s += p[e]; }
        float inv = 1.f / s;
        int i1 = 0; float b1 = p[0];
#pragma unroll
        for (int e = 1; e < NE; e++) if (p[e] > b1) { b1 = p[e]; i1 = e; }
        int i2 = (i1 == 0) ? 1 : 0; float b2 = p[i2];
#pragma unroll
        for (int e = 0; e < NE; e++) if (e != i1 && p[e] > b2) { b2 = p[e]; i2 = e; }
        int pos0 = atomicAdd(&counts[i1], 1);
        lists[i1 * NT + pos0] = 2 * t;
        int pos1 = atomicAdd(&counts[i2], 1);
        lists[i2 * NT + pos1] = 2 * t + 1;
        gates[2 * t] = b1 * inv;
        gates[2 * t + 1] = b2 * inv;
    }
}

// Compact block table: one entry per active 256-row m-tile -> (expert, m0).
__global__ void k_plan(const int* __restrict__ counts, int2* __restrict__ table) {
    __shared__ int starts[NE + 1];
    const int tid = threadIdx.x;
    if (tid == 0) {
        int s = 0;
        for (int e = 0; e < NE; e++) { starts[e] = s; s += (counts[e] + 255) >> 8; }
        starts[NE] = s;
    }
    __syncthreads();
    for (int b = tid; b < MAXB; b += 256) {
        int e = -1, m0 = 0;
#pragma unroll
        for (int q = 0; q < NE; q++)
            if (b >= starts[q] && b < starts[q + 1]) { e = q; m0 = (b - starts[q]) << 8; }
        table[b].x = e; table[b].y = m0;
    }
}

// ---- GEMM structure ------------------------------------------------------
// Tile BM=256 x BN=128, BK=64, 8 waves (4M x 2N), 3 LDS buffers, depth-2 pipeline.
// LDS row-major [row][64] bf16 with XOR swizzle: 16B-chunk c stored at c^(row&7).
// Staging: wave window (i*8+wid)*1024B covers rows +0..7; lane (rsub=lane>>3,
// c=lane&7) fetches global chunk (lane&7)^rsub of its row -> contiguous 128B per
// 8 lanes (coalesced), swizzle realized via the global source (rule 21).
// Fragment reads: ds_read_b128 at chunk (s*4+(lane>>4))^(lane&7) -> 2 lanes/bank.

// GEMM1: h[slot] = gelu(x_gathered @ w1[e]^T).
__launch_bounds__(512, 2)
__global__ void k_gemm1(const unsigned short* __restrict__ xb, const unsigned short* __restrict__ w1b,
                        const int* __restrict__ lists, const int* __restrict__ counts,
                        const int2* __restrict__ table,
                        unsigned short* __restrict__ hbuf) {
    const int2 ent = table[blockIdx.x];
    const int e = ent.x;
    if (e < 0) return;
    const int m0 = ent.y;
    const int cnt = counts[e];
    const int n0 = blockIdx.y * BN;
    __shared__ __align__(16) unsigned short As[3 * ASZ];
    __shared__ __align__(16) unsigned short Bs[3 * BSZ];
    __shared__ int slot_s[BM];
    const int tid = threadIdx.x, lane = tid & 63, wid = tid >> 6;
    if (tid < BM) {
        int r = m0 + tid;
        slot_s[tid] = lists[e * NT + (r < cnt ? r : cnt - 1)];
    }
    __syncthreads();

    const int rsub = lane >> 3;
    const int sw = (((lane & 7) ^ rsub) * 8);          // swizzled element offset in row
    const unsigned short* gA[4];
#pragma unroll
    for (int i = 0; i < 4; i++) {
        int row = wid * 8 + rsub + 64 * i;             // window (i*8+wid), rows 0..255
        gA[i] = xb + (size_t)(slot_s[row] >> 1) * HD + sw;
    }
    const unsigned short* gB[2];
#pragma unroll
    for (int i = 0; i < 2; i++) {
        int row = wid * 8 + rsub + 64 * i;             // rows 0..127
        gB[i] = w1b + ((size_t)e * ID + n0 + row) * HD + sw;
    }
    auto stage = [&](int bf) {
#pragma unroll
        for (int i = 0; i < 4; i++) { gload16(gA[i], As + bf * ASZ + (i * 8 + wid) * 512); gA[i] += BK; }
#pragma unroll
        for (int i = 0; i < 2; i++) { gload16(gB[i], Bs + bf * BSZ + (i * 8 + wid) * 512); gB[i] += BK; }
    };

    const int wr = wid >> 1, wc = wid & 1;
    const int l15 = lane & 15, l4 = lane >> 4, l7 = lane & 7;
    const int aBase = (wr * 64 + l15) * 64;
    const int bBase = (wc * 64 + l15) * 64;
    const int c0 = ((l4) ^ l7) * 8;
    const int c1 = ((4 + l4) ^ l7) * 8;

    f32x4 acc[4][4];
    f32x4 zero = {0.f, 0.f, 0.f, 0.f};
#pragma unroll
    for (int m = 0; m < 4; m++)
#pragma unroll
        for (int n = 0; n < 4; n++) acc[m][n] = zero;

    const int NK = HD / BK;      // 12
    stage(0); stage(1);
    int cur = 0, pf = 2;
    for (int kt = 0; kt < NK; ++kt) {
        if (kt + 1 < NK) asm volatile("s_waitcnt vmcnt(6)\ns_barrier" ::: "memory");
        else             asm volatile("s_waitcnt vmcnt(0)\ns_barrier" ::: "memory");
        if (kt + 2 < NK) { stage(pf); pf = (pf == 2) ? 0 : pf + 1; }
        const unsigned short* Ab = As + cur * ASZ;
        const unsigned short* Bb = Bs + cur * BSZ;
#pragma unroll
        for (int s = 0; s < 2; s++) {
            const int cs = s ? c1 : c0;
            bf16x8 a[4], b[4];
#pragma unroll
            for (int m = 0; m < 4; m++) a[m] = *(const bf16x8*)(Ab + aBase + m * 1024 + cs);
#pragma unroll
            for (int n = 0; n < 4; n++) b[n] = *(const bf16x8*)(Bb + bBase + n * 1024 + cs);
#pragma unroll
            for (int m = 0; m < 4; m++)
#pragma unroll
                for (int n = 0; n < 4; n++)
                    acc[m][n] = __builtin_amdgcn_mfma_f32_16x16x32_bf16(a[m], b[n], acc[m][n], 0, 0, 0);
        }
        cur = (cur == 2) ? 0 : cur + 1;
    }
    const int rj = l4 * 4;
#pragma unroll
    for (int m = 0; m < 4; m++) {
#pragma unroll
        for (int j = 0; j < 4; j++) {
            int lr2 = wr * 64 + m * 16 + rj + j;
            if (m0 + lr2 < cnt) {
                int slot = slot_s[lr2];
                size_t rowoff = (size_t)slot * ID + n0 + wc * 64 + l15;
#pragma unroll
                for (int n = 0; n < 4; n++) {
                    float v = acc[m][n][j];
                    v = 0.5f * v * (1.f + erff(v * 0.70710678118654752f));  // exact gelu
                    hbuf[rowoff + n * 16] = f2bf(v);
                }
            }
        }
    }
}

// GEMM2: pout[slot] = gate[slot] * (h_gathered @ w2[e]^T). K=3072.
__launch_bounds__(512, 2)
__global__ void k_gemm2(const unsigned short* __restrict__ hbuf, const unsigned short* __restrict__ w2b,
                        const int* __restrict__ lists, const int* __restrict__ counts,
                        const int2* __restrict__ table,
                        const float* __restrict__ gates, float* __restrict__ pout) {
    const int2 ent = table[blockIdx.x];
    const int e = ent.x;
    if (e < 0) return;
    const int m0 = ent.y;
    const int cnt = counts[e];
    const int n0 = blockIdx.y * BN;
    __shared__ __align__(16) unsigned short As[3 * ASZ];
    __shared__ __align__(16) unsigned short Bs[3 * BSZ];
    __shared__ int slot_s[BM];
    const int tid = threadIdx.x, lane = tid & 63, wid = tid >> 6;
    if (tid < BM) {
        int r = m0 + tid;
        slot_s[tid] = lists[e * NT + (r < cnt ? r : cnt - 1)];
    }
    __syncthreads();

    const int rsub = lane >> 3;
    const int sw = (((lane & 7) ^ rsub) * 8);
    const unsigned short* gA[4];
#pragma unroll
    for (int i = 0; i < 4; i++) {
        int row = wid * 8 + rsub + 64 * i;
        gA[i] = hbuf + (size_t)slot_s[row] * ID + sw;
    }
    const unsigned short* gB[2];
#pragma unroll
    for (int i = 0; i < 2; i++) {
        int row = wid * 8 + rsub + 64 * i;
        gB[i] = w2b + ((size_t)e * HD + n0 + row) * ID + sw;
    }
    auto stage = [&](int bf) {
#pragma unroll
        for (int i = 0; i < 4; i++) { gload16(gA[i], As + bf * ASZ + (i * 8 + wid) * 512); gA[i] += BK; }
#pragma unroll
        for (int i = 0; i < 2; i++) { gload16(gB[i], Bs + bf * BSZ + (i * 8 + wid) * 512); gB[i] += BK; }
    };

    const int wr = wid >> 1, wc = wid & 1;
    const int l15 = lane & 15, l4 = lane >> 4, l7 = lane & 7;
    const int aBase = (wr * 64 + l15) * 64;
    const int bBase = (wc * 64 + l15) * 64;
    const int c0 = ((l4) ^ l7) * 8;
    const int c1 = ((4 + l4) ^ l7) * 8;

    f32x4 acc[4][4];
    f32x4 zero = {0.f, 0.f, 0.f, 0.f};
#pragma unroll
    for (int m = 0; m < 4; m++)
#pragma unroll
        for (int n = 0; n < 4; n++) acc[m][n] = zero;

    const int NK = ID / BK;      // 48
    stage(0); stage(1);
    int cur = 0, pf = 2;
    for (int kt = 0; kt < NK; ++kt) {
        if (kt + 1 < NK) asm volatile("s_waitcnt vmcnt(6)\ns_barrier" ::: "memory");
        else             asm volatile("s_waitcnt vmcnt(0)\ns_barrier" ::: "memory");
        if (kt + 2 < NK) { stage(pf); pf = (pf == 2) ? 0 : pf + 1; }
        const unsigned short* Ab = As + cur * ASZ;
        const unsigned short* Bb = Bs + cur * BSZ;
#pragma unroll
        for (int s = 0; s < 2; s++) {
            const int cs = s ? c1 : c0;
            bf16x8 a[4], b[4];
#pragma unroll
            for (int m = 0; m < 4; m++) a[m] = *(const bf16x8*)(Ab + aBase + m * 1024 + cs);
#pragma unroll
            for (int n = 0; n < 4; n++) b[n] = *(const bf16x8*)(Bb + bBase + n * 1024 + cs);
#pragma unroll
            for (int m = 0; m < 4; m++)
#pragma unroll
                for (int n = 0; n < 4; n++)
                    acc[m][n] = __builtin_amdgcn_mfma_f32_16x16x32_bf16(a[m], b[n], acc[m][n], 0, 0, 0);
        }
        cur = (cur == 2) ? 0 : cur + 1;
    }
    const int rj = l4 * 4;
#pragma unroll
    for (int m = 0; m < 4; m++) {
#pragma unroll
        for (int j = 0; j < 4; j++) {
            int lr2 = wr * 64 + m * 16 + rj + j;
            if (m0 + lr2 < cnt) {
                int slot = slot_s[lr2];
                float g = gates[slot];
                size_t rowoff = (size_t)slot * HD + n0 + wc * 64 + l15;
#pragma unroll
                for (int n = 0; n < 4; n++)
                    pout[rowoff + n * 16] = g * acc[m][n][j];
            }
        }
    }
}

// out[t] = pout[2t] + pout[2t+1] + bias
__global__ void k_combine(const float4* __restrict__ pout, const float* __restrict__ bias,
                          float4* __restrict__ out) {
    int idx = blockIdx.x * 256 + threadIdx.x;   // over NT*HD/4
    int t = idx / (HD / 4);
    int c = idx - t * (HD / 4);
    float4 a = pout[(size_t)t * (2 * HD / 4) + c];
    float4 b = pout[(size_t)t * (2 * HD / 4) + HD / 4 + c];
    float4 bb = ((const float4*)bias)[c];
    float4 r;
    r.x = a.x + b.x + bb.x; r.y = a.y + b.y + bb.y;
    r.z = a.z + b.z + bb.z; r.w = a.w + b.w + bb.w;
    out[idx] = r;
}

extern "C" void kernel_launch(void* const* d_in, const int* in_sizes, int n_in,
                              void* d_out, int out_size, void* d_ws, size_t ws_size,
                              hipStream_t stream) {
    const float* x    = (const float*)d_in[0];
    const float* rw   = (const float*)d_in[1];
    const float* w1   = (const float*)d_in[2];
    const float* w2   = (const float*)d_in[3];
    const float* bias = (const float*)d_in[4];
    float* out = (float*)d_out;

    char* ws = (char*)d_ws;
    size_t off = 0;
    auto alloc = [&](size_t bytes) -> char* {
        char* p = ws + off;
        off += (bytes + 255) & ~(size_t)255;
        return p;
    };
    int*            counts = (int*)alloc(NE * 4);
    int2*           table  = (int2*)alloc(MAXB * sizeof(int2));
    int*            lists  = (int*)alloc((size_t)NE * NT * 4);
    float*          gates  = (float*)alloc((size_t)NT * 2 * 4);
    unsigned short* xb     = (unsigned short*)alloc((size_t)NT * HD * 2);
    unsigned short* w1b    = (unsigned short*)alloc((size_t)NE * ID * HD * 2);
    unsigned short* w2b    = (unsigned short*)alloc((size_t)NE * HD * ID * 2);
    unsigned short* hbuf   = (unsigned short*)alloc((size_t)NT * 2 * ID * 2);
    float*          pout   = (float*)alloc((size_t)NT * 2 * HD * 4);

    k_init<<<dim3(1), dim3(64), 0, stream>>>(counts);
    const int n4 = NE * ID * HD / 4;
    k_convertw<<<dim3((n4 + 255) / 256), dim3(256), 0, stream>>>(
        (const float4*)w1, (const float4*)w2, (ushort4*)w1b, (ushort4*)w2b, n4);
    k_router<<<dim3(NT / 4), dim3(256), 0, stream>>>(x, rw, xb, gates, lists, counts);
    k_plan<<<dim3(1), dim3(256), 0, stream>>>(counts, table);
    k_gemm1<<<dim3(MAXB, ID / BN), dim3(512), 0, stream>>>(xb, w1b, lists, counts, table, hbuf);
    k_gemm2<<<dim3(MAXB, HD / BN), dim3(512), 0, stream>>>(hbuf, w2b, lists, counts, table, gates, pout);
    k_combine<<<dim3(NT * HD / 4 / 256), dim3(256), 0, stream>>>((const float4*)pout, bias, (float4*)out);
}

// Round 5
// 350.247 us; speedup vs baseline: 2.0471x; 1.3928x over previous
//
#include <hip/hip_runtime.h>
#include <hip/hip_bf16.h>
#include <math.h>

#define NT 8192
#define HD 768
#define ID 3072
#define NE 8
#define BM 256
#define BN 128
#define BK 64
#define MAXB 72    // >= sum_e ceil(cnt_e/256), sum cnt = 16384
#define ASZ (BM * BK)   // shorts per A buffer (16384)
#define BSZ (BN * BK)   // shorts per B buffer (8192)

typedef __bf16 bf16x8 __attribute__((ext_vector_type(8)));
typedef float f32x4 __attribute__((ext_vector_type(4)));

__device__ __forceinline__ unsigned short f2bf(float f) {
    union { float f; unsigned u; } v; v.f = f;
    unsigned r = v.u + 0x7FFFu + ((v.u >> 16) & 1u);   // RNE
    return (unsigned short)(r >> 16);
}
__device__ __forceinline__ float bf2f(unsigned short b) {
    union { unsigned u; float f; } v; v.u = ((unsigned)b) << 16;
    return v.f;
}

// global->LDS direct copy, 16B/lane. LDS dest = wave-uniform base + lane*16.
__device__ __forceinline__ void gload16(const void* g, void* l) {
    auto* lds = reinterpret_cast<__attribute__((address_space(3))) unsigned int*>(
        reinterpret_cast<uintptr_t>(l));
    auto* gp = reinterpret_cast<const __attribute__((address_space(1))) unsigned int*>(
        reinterpret_cast<uintptr_t>(g));
    __builtin_amdgcn_global_load_lds(gp, lds, 16, 0, 0);
}

__global__ void k_convertw(const float4* __restrict__ w1, const float4* __restrict__ w2,
                           ushort4* __restrict__ w1b, ushort4* __restrict__ w2b, int n) {
    int i = blockIdx.x * 256 + threadIdx.x;
    if (i >= n) return;
    float4 a = w1[i]; float4 b = w2[i];
    ushort4 ra, rb;
    ra.x = f2bf(a.x); ra.y = f2bf(a.y); ra.z = f2bf(a.z); ra.w = f2bf(a.w);
    rb.x = f2bf(b.x); rb.y = f2bf(b.y); rb.z = f2bf(b.z); rb.w = f2bf(b.w);
    w1b[i] = ra; w2b[i] = rb;
}

// Router phase 1: exact fp32 logits/softmax/top-2 (ties -> lowest index).
// Writes per-token expert choice + gates + x in bf16. NO atomics.
// 4 waves/block, 8 tokens/wave sequentially.
__global__ void k_router(const float* __restrict__ x, const float* __restrict__ rw,
                         unsigned short* __restrict__ xb, float* __restrict__ gates,
                         uchar2* __restrict__ choice) {
    __shared__ float rws[NE * HD];
    const int tid = threadIdx.x;
    for (int i = tid; i < NE * HD; i += 256) rws[i] = rw[i];
    __syncthreads();
    const int wid = tid >> 6, lane = tid & 63;
    for (int it = 0; it < 8; ++it) {
        const int t = blockIdx.x * 32 + wid * 8 + it;
        const float* xp = x + (size_t)t * HD;
        float acc[NE];
#pragma unroll
        for (int e = 0; e < NE; e++) acc[e] = 0.f;
#pragma unroll
        for (int j = 0; j < HD / 64; j++) {
            float v = xp[lane + 64 * j];
            xb[(size_t)t * HD + lane + 64 * j] = f2bf(v);
#pragma unroll
            for (int e = 0; e < NE; e++) acc[e] += v * rws[e * HD + lane + 64 * j];
        }
#pragma unroll
        for (int e = 0; e < NE; e++)
            for (int off = 32; off; off >>= 1) acc[e] += __shfl_xor(acc[e], off);
        if (lane == 0) {
            float mx = acc[0];
#pragma unroll
            for (int e = 1; e < NE; e++) mx = fmaxf(mx, acc[e]);
            float p[NE], s = 0.f;
#pragma unroll
            for (int e = 0; e < NE; e++) { p[e] = __expf(acc[e] - mx); s += p[e]; }
            float inv = 1.f / s;
            int i1 = 0; float b1 = p[0];
#pragma unroll
            for (int e = 1; e < NE; e++) if (p[e] > b1) { b1 = p[e]; i1 = e; }
            int i2 = (i1 == 0) ? 1 : 0; float b2 = p[i2];
#pragma unroll
            for (int e = 0; e < NE; e++) if (e != i1 && p[e] > b2) { b2 = p[e]; i2 = e; }
            choice[t].x = (unsigned char)i1;
            choice[t].y = (unsigned char)i2;
            gates[2 * t] = b1 * inv;
            gates[2 * t + 1] = b2 * inv;
        }
    }
}

// Router phase 2: one block per expert; ballot/prefix-scan compaction of the
// token slots choosing this expert. Zero atomics; deterministic order.
// Top-2 ids are distinct, so each token matches expert e at most once.
__global__ void k_scatter(const uchar2* __restrict__ choice,
                          int* __restrict__ lists, int* __restrict__ counts) {
    const int e = blockIdx.x;
    const int tid = threadIdx.x, wid = tid >> 6, lane = tid & 63;
    __shared__ int wtot[4];
    __shared__ int running;
    if (tid == 0) running = 0;
    __syncthreads();
    for (int t0 = 0; t0 < NT; t0 += 256) {
        const int t = t0 + tid;
        uchar2 c = choice[t];
        bool m1 = (c.x == e), m2 = (c.y == e);
        bool m = m1 || m2;
        int slot = m1 ? 2 * t : 2 * t + 1;
        unsigned long long mask = __ballot(m);
        int off = __popcll(mask & ((1ULL << lane) - 1ULL));
        if (lane == 0) wtot[wid] = __popcll(mask);
        __syncthreads();
        int base = running;
        for (int w = 0; w < wid; w++) base += wtot[w];
        if (m) lists[e * NT + base + off] = slot;
        __syncthreads();
        if (tid == 0) running += wtot[0] + wtot[1] + wtot[2] + wtot[3];
        __syncthreads();
    }
    if (tid == 0) counts[e] = running;
}

// Compact block table: one entry per active 256-row m-tile -> (expert, m0).
__global__ void k_plan(const int* __restrict__ counts, int2* __restrict__ table) {
    __shared__ int starts[NE + 1];
    const int tid = threadIdx.x;
    if (tid == 0) {
        int s = 0;
        for (int e = 0; e < NE; e++) { starts[e] = s; s += (counts[e] + 255) >> 8; }
        starts[NE] = s;
    }
    __syncthreads();
    for (int b = tid; b < MAXB; b += 256) {
        int e = -1, m0 = 0;
#pragma unroll
        for (int q = 0; q < NE; q++)
            if (b >= starts[q] && b < starts[q + 1]) { e = q; m0 = (b - starts[q]) << 8; }
        table[b].x = e; table[b].y = m0;
    }
}

// ---- GEMM structure ------------------------------------------------------
// Tile BM=256 x BN=128, BK=64, 8 waves (4M x 2N), 3 LDS buffers, depth-2 pipeline.
// LDS row-major [row][64] bf16 with XOR swizzle: 16B-chunk c stored at c^(row&7).
// Coalesced staging via pre-swizzled global source; conflict-free ds_read_b128.

// GEMM1: h[slot] = gelu(x_gathered @ w1[e]^T).
__launch_bounds__(512, 2)
__global__ void k_gemm1(const unsigned short* __restrict__ xb, const unsigned short* __restrict__ w1b,
                        const int* __restrict__ lists, const int* __restrict__ counts,
                        const int2* __restrict__ table,
                        unsigned short* __restrict__ hbuf) {
    const int2 ent = table[blockIdx.x];
    const int e = ent.x;
    if (e < 0) return;
    const int m0 = ent.y;
    const int cnt = counts[e];
    const int n0 = blockIdx.y * BN;
    __shared__ __align__(16) unsigned short As[3 * ASZ];
    __shared__ __align__(16) unsigned short Bs[3 * BSZ];
    __shared__ int slot_s[BM];
    const int tid = threadIdx.x, lane = tid & 63, wid = tid >> 6;
    if (tid < BM) {
        int r = m0 + tid;
        slot_s[tid] = lists[e * NT + (r < cnt ? r : cnt - 1)];
    }
    __syncthreads();

    const int rsub = lane >> 3;
    const int sw = (((lane & 7) ^ rsub) * 8);          // swizzled element offset in row
    const unsigned short* gA[4];
#pragma unroll
    for (int i = 0; i < 4; i++) {
        int row = wid * 8 + rsub + 64 * i;             // window (i*8+wid), rows 0..255
        gA[i] = xb + (size_t)(slot_s[row] >> 1) * HD + sw;
    }
    const unsigned short* gB[2];
#pragma unroll
    for (int i = 0; i < 2; i++) {
        int row = wid * 8 + rsub + 64 * i;             // rows 0..127
        gB[i] = w1b + ((size_t)e * ID + n0 + row) * HD + sw;
    }
    auto stage = [&](int bf) {
#pragma unroll
        for (int i = 0; i < 4; i++) { gload16(gA[i], As + bf * ASZ + (i * 8 + wid) * 512); gA[i] += BK; }
#pragma unroll
        for (int i = 0; i < 2; i++) { gload16(gB[i], Bs + bf * BSZ + (i * 8 + wid) * 512); gB[i] += BK; }
    };

    const int wr = wid >> 1, wc = wid & 1;
    const int l15 = lane & 15, l4 = lane >> 4, l7 = lane & 7;
    const int aBase = (wr * 64 + l15) * 64;
    const int bBase = (wc * 64 + l15) * 64;
    const int c0 = ((l4) ^ l7) * 8;
    const int c1 = ((4 + l4) ^ l7) * 8;

    f32x4 acc[4][4];
    f32x4 zero = {0.f, 0.f, 0.f, 0.f};
#pragma unroll
    for (int m = 0; m < 4; m++)
#pragma unroll
        for (int n = 0; n < 4; n++) acc[m][n] = zero;

    const int NK = HD / BK;      // 12
    stage(0); stage(1);
    int cur = 0, pf = 2;
    for (int kt = 0; kt < NK; ++kt) {
        if (kt + 1 < NK) asm volatile("s_waitcnt vmcnt(6)\ns_barrier" ::: "memory");
        else             asm volatile("s_waitcnt vmcnt(0)\ns_barrier" ::: "memory");
        if (kt + 2 < NK) { stage(pf); pf = (pf == 2) ? 0 : pf + 1; }
        const unsigned short* Ab = As + cur * ASZ;
        const unsigned short* Bb = Bs + cur * BSZ;
#pragma unroll
        for (int s = 0; s < 2; s++) {
            const int cs = s ? c1 : c0;
            bf16x8 a[4], b[4];
#pragma unroll
            for (int m = 0; m < 4; m++) a[m] = *(const bf16x8*)(Ab + aBase + m * 1024 + cs);
#pragma unroll
            for (int n = 0; n < 4; n++) b[n] = *(const bf16x8*)(Bb + bBase + n * 1024 + cs);
#pragma unroll
            for (int m = 0; m < 4; m++)
#pragma unroll
                for (int n = 0; n < 4; n++)
                    acc[m][n] = __builtin_amdgcn_mfma_f32_16x16x32_bf16(a[m], b[n], acc[m][n], 0, 0, 0);
        }
        cur = (cur == 2) ? 0 : cur + 1;
    }
    const int rj = l4 * 4;
#pragma unroll
    for (int m = 0; m < 4; m++) {
#pragma unroll
        for (int j = 0; j < 4; j++) {
            int lr2 = wr * 64 + m * 16 + rj + j;
            if (m0 + lr2 < cnt) {
                int slot = slot_s[lr2];
                size_t rowoff = (size_t)slot * ID + n0 + wc * 64 + l15;
#pragma unroll
                for (int n = 0; n < 4; n++) {
                    float v = acc[m][n][j];
                    v = 0.5f * v * (1.f + erff(v * 0.70710678118654752f));  // exact gelu
                    hbuf[rowoff + n * 16] = f2bf(v);
                }
            }
        }
    }
}

// GEMM2: pout[slot] = gate[slot] * (h_gathered @ w2[e]^T). K=3072. bf16 partials.
__launch_bounds__(512, 2)
__global__ void k_gemm2(const unsigned short* __restrict__ hbuf, const unsigned short* __restrict__ w2b,
                        const int* __restrict__ lists, const int* __restrict__ counts,
                        const int2* __restrict__ table,
                        const float* __restrict__ gates, unsigned short* __restrict__ pout) {
    const int2 ent = table[blockIdx.x];
    const int e = ent.x;
    if (e < 0) return;
    const int m0 = ent.y;
    const int cnt = counts[e];
    const int n0 = blockIdx.y * BN;
    __shared__ __align__(16) unsigned short As[3 * ASZ];
    __shared__ __align__(16) unsigned short Bs[3 * BSZ];
    __shared__ int slot_s[BM];
    const int tid = threadIdx.x, lane = tid & 63, wid = tid >> 6;
    if (tid < BM) {
        int r = m0 + tid;
        slot_s[tid] = lists[e * NT + (r < cnt ? r : cnt - 1)];
    }
    __syncthreads();

    const int rsub = lane >> 3;
    const int sw = (((lane & 7) ^ rsub) * 8);
    const unsigned short* gA[4];
#pragma unroll
    for (int i = 0; i < 4; i++) {
        int row = wid * 8 + rsub + 64 * i;
        gA[i] = hbuf + (size_t)slot_s[row] * ID + sw;
    }
    const unsigned short* gB[2];
#pragma unroll
    for (int i = 0; i < 2; i++) {
        int row = wid * 8 + rsub + 64 * i;
        gB[i] = w2b + ((size_t)e * HD + n0 + row) * ID + sw;
    }
    auto stage = [&](int bf) {
#pragma unroll
        for (int i = 0; i < 4; i++) { gload16(gA[i], As + bf * ASZ + (i * 8 + wid) * 512); gA[i] += BK; }
#pragma unroll
        for (int i = 0; i < 2; i++) { gload16(gB[i], Bs + bf * BSZ + (i * 8 + wid) * 512); gB[i] += BK; }
    };

    const int wr = wid >> 1, wc = wid & 1;
    const int l15 = lane & 15, l4 = lane >> 4, l7 = lane & 7;
    const int aBase = (wr * 64 + l15) * 64;
    const int bBase = (wc * 64 + l15) * 64;
    const int c0 = ((l4) ^ l7) * 8;
    const int c1 = ((4 + l4) ^ l7) * 8;

    f32x4 acc[4][4];
    f32x4 zero = {0.f, 0.f, 0.f, 0.f};
#pragma unroll
    for (int m = 0; m < 4; m++)
#pragma unroll
        for (int n = 0; n < 4; n++) acc[m][n] = zero;

    const int NK = ID / BK;      // 48
    stage(0); stage(1);
    int cur = 0, pf = 2;
    for (int kt = 0; kt < NK; ++kt) {
        if (kt + 1 < NK) asm volatile("s_waitcnt vmcnt(6)\ns_barrier" ::: "memory");
        else             asm volatile("s_waitcnt vmcnt(0)\ns_barrier" ::: "memory");
        if (kt + 2 < NK) { stage(pf); pf = (pf == 2) ? 0 : pf + 1; }
        const unsigned short* Ab = As + cur * ASZ;
        const unsigned short* Bb = Bs + cur * BSZ;
#pragma unroll
        for (int s = 0; s < 2; s++) {
            const int cs = s ? c1 : c0;
            bf16x8 a[4], b[4];
#pragma unroll
            for (int m = 0; m < 4; m++) a[m] = *(const bf16x8*)(Ab + aBase + m * 1024 + cs);
#pragma unroll
            for (int n = 0; n < 4; n++) b[n] = *(const bf16x8*)(Bb + bBase + n * 1024 + cs);
#pragma unroll
            for (int m = 0; m < 4; m++)
#pragma unroll
                for (int n = 0; n < 4; n++)
                    acc[m][n] = __builtin_amdgcn_mfma_f32_16x16x32_bf16(a[m], b[n], acc[m][n], 0, 0, 0);
        }
        cur = (cur == 2) ? 0 : cur + 1;
    }
    const int rj = l4 * 4;
#pragma unroll
    for (int m = 0; m < 4; m++) {
#pragma unroll
        for (int j = 0; j < 4; j++) {
            int lr2 = wr * 64 + m * 16 + rj + j;
            if (m0 + lr2 < cnt) {
                int slot = slot_s[lr2];
                float g = gates[slot];
                size_t rowoff = (size_t)slot * HD + n0 + wc * 64 + l15;
#pragma unroll
                for (int n = 0; n < 4; n++)
                    pout[rowoff + n * 16] = f2bf(g * acc[m][n][j]);
            }
        }
    }
}

// out[t] = pout[2t] + pout[2t+1] + bias   (pout is bf16)
__global__ void k_combine(const unsigned short* __restrict__ pout, const float* __restrict__ bias,
                          float4* __restrict__ out) {
    int idx = blockIdx.x * 256 + threadIdx.x;   // over NT*HD/4
    int t = idx / (HD / 4);
    int c = idx - t * (HD / 4);
    ushort4 a = ((const ushort4*)pout)[(size_t)t * (2 * HD / 4) + c];
    ushort4 b = ((const ushort4*)pout)[(size_t)t * (2 * HD / 4) + HD / 4 + c];
    float4 bb = ((const float4*)bias)[c];
    float4 r;
    r.x = bf2f(a.x) + bf2f(b.x) + bb.x;
    r.y = bf2f(a.y) + bf2f(b.y) + bb.y;
    r.z = bf2f(a.z) + bf2f(b.z) + bb.z;
    r.w = bf2f(a.w) + bf2f(b.w) + bb.w;
    out[idx] = r;
}

extern "C" void kernel_launch(void* const* d_in, const int* in_sizes, int n_in,
                              void* d_out, int out_size, void* d_ws, size_t ws_size,
                              hipStream_t stream) {
    const float* x    = (const float*)d_in[0];
    const float* rw   = (const float*)d_in[1];
    const float* w1   = (const float*)d_in[2];
    const float* w2   = (const float*)d_in[3];
    const float* bias = (const float*)d_in[4];
    float* out = (float*)d_out;

    char* ws = (char*)d_ws;
    size_t off = 0;
    auto alloc = [&](size_t bytes) -> char* {
        char* p = ws + off;
        off += (bytes + 255) & ~(size_t)255;
        return p;
    };
    int*            counts = (int*)alloc(NE * 4);
    int2*           table  = (int2*)alloc(MAXB * sizeof(int2));
    int*            lists  = (int*)alloc((size_t)NE * NT * 4);
    float*          gates  = (float*)alloc((size_t)NT * 2 * 4);
    uchar2*         choice = (uchar2*)alloc((size_t)NT * 2);
    unsigned short* xb     = (unsigned short*)alloc((size_t)NT * HD * 2);
    unsigned short* w1b    = (unsigned short*)alloc((size_t)NE * ID * HD * 2);
    unsigned short* w2b    = (unsigned short*)alloc((size_t)NE * HD * ID * 2);
    unsigned short* hbuf   = (unsigned short*)alloc((size_t)NT * 2 * ID * 2);
    unsigned short* pout   = (unsigned short*)alloc((size_t)NT * 2 * HD * 2);

    const int n4 = NE * ID * HD / 4;
    k_convertw<<<dim3((n4 + 255) / 256), dim3(256), 0, stream>>>(
        (const float4*)w1, (const float4*)w2, (ushort4*)w1b, (ushort4*)w2b, n4);
    k_router<<<dim3(NT / 32), dim3(256), 0, stream>>>(x, rw, xb, gates, choice);
    k_scatter<<<dim3(NE), dim3(256), 0, stream>>>(choice, lists, counts);
    k_plan<<<dim3(1), dim3(256), 0, stream>>>(counts, table);
    k_gemm1<<<dim3(MAXB, ID / BN), dim3(512), 0, stream>>>(xb, w1b, lists, counts, table, hbuf);
    k_gemm2<<<dim3(MAXB, HD / BN), dim3(512), 0, stream>>>(hbuf, w2b, lists, counts, table, gates, pout);
    k_combine<<<dim3(NT * HD / 4 / 256), dim3(256), 0, stream>>>(pout, bias, (float4*)out);
}

// Round 6
// 341.306 us; speedup vs baseline: 2.1007x; 1.0262x over previous
//
#include <hip/hip_runtime.h>
#include <hip/hip_bf16.h>
#include <math.h>

#define NT 8192
#define HD 768
#define ID 3072
#define NE 8
#define BM 256
#define BN 128
#define BK 32
#define MAXB 72    // >= sum_e ceil(cnt_e/256); 72 % 8 == 0 for XCD swizzle
#define ASZ (BM * BK)   // shorts per A buffer (8192)
#define BSZ (BN * BK)   // shorts per B buffer (4096)

typedef __bf16 bf16x8 __attribute__((ext_vector_type(8)));
typedef float f32x4 __attribute__((ext_vector_type(4)));

__device__ __forceinline__ unsigned short f2bf(float f) {
    union { float f; unsigned u; } v; v.f = f;
    unsigned r = v.u + 0x7FFFu + ((v.u >> 16) & 1u);   // RNE
    return (unsigned short)(r >> 16);
}
__device__ __forceinline__ float bf2f(unsigned short b) {
    union { unsigned u; float f; } v; v.u = ((unsigned)b) << 16;
    return v.f;
}

// global->LDS direct copy, 16B/lane. LDS dest = wave-uniform base + lane*16.
__device__ __forceinline__ void gload16(const void* g, void* l) {
    auto* lds = reinterpret_cast<__attribute__((address_space(3))) unsigned int*>(
        reinterpret_cast<uintptr_t>(l));
    auto* gp = reinterpret_cast<const __attribute__((address_space(1))) unsigned int*>(
        reinterpret_cast<uintptr_t>(g));
    __builtin_amdgcn_global_load_lds(gp, lds, 16, 0, 0);
}

__global__ void k_convertw(const float4* __restrict__ w1, const float4* __restrict__ w2,
                           ushort4* __restrict__ w1b, ushort4* __restrict__ w2b, int n) {
    int i = blockIdx.x * 256 + threadIdx.x;
    if (i >= n) return;
    float4 a = w1[i]; float4 b = w2[i];
    ushort4 ra, rb;
    ra.x = f2bf(a.x); ra.y = f2bf(a.y); ra.z = f2bf(a.z); ra.w = f2bf(a.w);
    rb.x = f2bf(b.x); rb.y = f2bf(b.y); rb.z = f2bf(b.z); rb.w = f2bf(b.w);
    w1b[i] = ra; w2b[i] = rb;
}

// Router phase 1: exact fp32 logits/softmax/top-2 (ties -> lowest index).
// float4 loads; writes per-token choice + gates + x in bf16. NO atomics.
__global__ void k_router(const float* __restrict__ x, const float* __restrict__ rw,
                         ushort4* __restrict__ xb4, float* __restrict__ gates,
                         uchar2* __restrict__ choice) {
    __shared__ float rws[NE * HD];
    const int tid = threadIdx.x;
    for (int i = tid; i < NE * HD / 4; i += 256)
        ((float4*)rws)[i] = ((const float4*)rw)[i];
    __syncthreads();
    const int wid = tid >> 6, lane = tid & 63;
    const float4* rws4 = (const float4*)rws;
    for (int it = 0; it < 8; ++it) {
        const int t = blockIdx.x * 32 + wid * 8 + it;
        const float4* xp4 = (const float4*)(x + (size_t)t * HD);   // HD/4 = 192
        float acc[NE];
#pragma unroll
        for (int e = 0; e < NE; e++) acc[e] = 0.f;
#pragma unroll
        for (int j = 0; j < HD / 256; j++) {                        // 3 float4 per lane
            float4 v = xp4[lane + 64 * j];
            ushort4 o;
            o.x = f2bf(v.x); o.y = f2bf(v.y); o.z = f2bf(v.z); o.w = f2bf(v.w);
            xb4[(size_t)t * (HD / 4) + lane + 64 * j] = o;
#pragma unroll
            for (int e = 0; e < NE; e++) {
                float4 w = rws4[e * (HD / 4) + lane + 64 * j];
                acc[e] += v.x * w.x + v.y * w.y + v.z * w.z + v.w * w.w;
            }
        }
#pragma unroll
        for (int e = 0; e < NE; e++)
            for (int off = 32; off; off >>= 1) acc[e] += __shfl_xor(acc[e], off);
        if (lane == 0) {
            float mx = acc[0];
#pragma unroll
            for (int e = 1; e < NE; e++) mx = fmaxf(mx, acc[e]);
            float p[NE], s = 0.f;
#pragma unroll
            for (int e = 0; e < NE; e++) { p[e] = __expf(acc[e] - mx); s += p[e]; }
            float inv = 1.f / s;
            int i1 = 0; float b1 = p[0];
#pragma unroll
            for (int e = 1; e < NE; e++) if (p[e] > b1) { b1 = p[e]; i1 = e; }
            int i2 = (i1 == 0) ? 1 : 0; float b2 = p[i2];
#pragma unroll
            for (int e = 0; e < NE; e++) if (e != i1 && p[e] > b2) { b2 = p[e]; i2 = e; }
            choice[t].x = (unsigned char)i1;
            choice[t].y = (unsigned char)i2;
            gates[2 * t] = b1 * inv;
            gates[2 * t + 1] = b2 * inv;
        }
    }
}

// Router phase 2: one block per expert; ballot/prefix-scan compaction. No atomics.
__global__ void k_scatter(const uchar2* __restrict__ choice,
                          int* __restrict__ lists, int* __restrict__ counts) {
    const int e = blockIdx.x;
    const int tid = threadIdx.x, wid = tid >> 6, lane = tid & 63;
    __shared__ int wtot[4];
    __shared__ int running;
    if (tid == 0) running = 0;
    __syncthreads();
    for (int t0 = 0; t0 < NT; t0 += 256) {
        const int t = t0 + tid;
        uchar2 c = choice[t];
        bool m1 = (c.x == e), m2 = (c.y == e);
        bool m = m1 || m2;
        int slot = m1 ? 2 * t : 2 * t + 1;
        unsigned long long mask = __ballot(m);
        int off = __popcll(mask & ((1ULL << lane) - 1ULL));
        if (lane == 0) wtot[wid] = __popcll(mask);
        __syncthreads();
        int base = running;
        for (int w = 0; w < wid; w++) base += wtot[w];
        if (m) lists[e * NT + base + off] = slot;
        __syncthreads();
        if (tid == 0) running += wtot[0] + wtot[1] + wtot[2] + wtot[3];
        __syncthreads();
    }
    if (tid == 0) counts[e] = running;
}

// Compact block table: one entry per active 256-row m-tile -> (expert, m0).
__global__ void k_plan(const int* __restrict__ counts, int2* __restrict__ table) {
    __shared__ int starts[NE + 1];
    const int tid = threadIdx.x;
    if (tid == 0) {
        int s = 0;
        for (int e = 0; e < NE; e++) { starts[e] = s; s += (counts[e] + 255) >> 8; }
        starts[NE] = s;
    }
    __syncthreads();
    for (int b = tid; b < MAXB; b += 256) {
        int e = -1, m0 = 0;
#pragma unroll
        for (int q = 0; q < NE; q++)
            if (b >= starts[q] && b < starts[q + 1]) { e = q; m0 = (b - starts[q]) << 8; }
        table[b].x = e; table[b].y = m0;
    }
}

// ---- GEMM structure ------------------------------------------------------
// Tile 256x128, BK=32, 8 waves (4M x 2N), 3 LDS buffers (73 KB -> 2 blocks/CU),
// depth-2 counted-vmcnt pipeline (3 loads/wave/stage, wait vmcnt(3)).
// LDS rows 64 B (4 chunks of 16 B); chunk c of row r stored at c ^ key(r),
// key(r) = (r&3)^((r>>2)&3). Staging stays coalesced (8-lane groups cover a
// permuted-but-contiguous 64 B of one row); ds_read_b128 is 2-way (free).
// XCD swizzle: lx = (bx&7)*(MAXB/8) + bx>>3 -> each XCD owns 9 contiguous
// m-entries (same expert) -> B panels L2-resident. gridDim.x = 72 = 0 mod 8.

__device__ __forceinline__ int xcd_swz(int bx) {
    return (bx & 7) * (MAXB >> 3) + (bx >> 3);
}

// GEMM1: h[slot] = gelu(x_gathered @ w1[e]^T).
__launch_bounds__(512, 2)
__global__ void k_gemm1(const unsigned short* __restrict__ xb, const unsigned short* __restrict__ w1b,
                        const int* __restrict__ lists, const int* __restrict__ counts,
                        const int2* __restrict__ table,
                        unsigned short* __restrict__ hbuf) {
    const int2 ent = table[xcd_swz(blockIdx.x)];
    const int e = ent.x;
    if (e < 0) return;
    const int m0 = ent.y;
    const int cnt = counts[e];
    const int n0 = blockIdx.y * BN;
    __shared__ __align__(16) unsigned short As[3 * ASZ];
    __shared__ __align__(16) unsigned short Bs[3 * BSZ];
    __shared__ int slot_s[BM];
    const int tid = threadIdx.x, lane = tid & 63, wid = tid >> 6;
    if (tid < BM) {
        int r = m0 + tid;
        slot_s[tid] = lists[e * NT + (r < cnt ? r : cnt - 1)];
    }
    __syncthreads();

    const int rsub = lane >> 2;                              // 0..15 row in window
    const int keyS = (rsub & 3) ^ ((rsub >> 2) & 3);
    const int sw = ((lane & 3) ^ keyS) * 8;                  // global elem offset in row
    const unsigned short* gA[2];
#pragma unroll
    for (int i = 0; i < 2; i++) {
        int row = wid * 16 + rsub + 128 * i;                 // windows wid, wid+8
        gA[i] = xb + (size_t)(slot_s[row] >> 1) * HD + sw;
    }
    const unsigned short* gB = w1b + ((size_t)e * ID + n0 + wid * 16 + rsub) * HD + sw;
    auto stage = [&](int bf) {
#pragma unroll
        for (int i = 0; i < 2; i++) { gload16(gA[i], As + bf * ASZ + (wid + 8 * i) * 512); gA[i] += BK; }
        gload16(gB, Bs + bf * BSZ + wid * 512); gB += BK;
    };

    const int wr = wid >> 1, wc = wid & 1;
    const int l15 = lane & 15, l4 = lane >> 4;
    const int keyF = (l15 & 3) ^ ((l15 >> 2) & 3);
    const int aBase = (wr * 64 + l15) * BK;
    const int bBase = (wc * 64 + l15) * BK;
    const int cs = (l4 ^ keyF) * 8;

    f32x4 acc[4][4];
    f32x4 zero = {0.f, 0.f, 0.f, 0.f};
#pragma unroll
    for (int m = 0; m < 4; m++)
#pragma unroll
        for (int n = 0; n < 4; n++) acc[m][n] = zero;

    const int NK = HD / BK;      // 24
    stage(0); stage(1);
    int cur = 0, pf = 2;
    for (int kt = 0; kt < NK; ++kt) {
        if (kt + 1 < NK) asm volatile("s_waitcnt vmcnt(3)\ns_barrier" ::: "memory");
        else             asm volatile("s_waitcnt vmcnt(0)\ns_barrier" ::: "memory");
        if (kt + 2 < NK) { stage(pf); pf = (pf == 2) ? 0 : pf + 1; }
        const unsigned short* Ab = As + cur * ASZ;
        const unsigned short* Bb = Bs + cur * BSZ;
        bf16x8 a[4], b[4];
#pragma unroll
        for (int m = 0; m < 4; m++) a[m] = *(const bf16x8*)(Ab + aBase + m * 512 + cs);
#pragma unroll
        for (int n = 0; n < 4; n++) b[n] = *(const bf16x8*)(Bb + bBase + n * 512 + cs);
#pragma unroll
        for (int m = 0; m < 4; m++)
#pragma unroll
            for (int n = 0; n < 4; n++)
                acc[m][n] = __builtin_amdgcn_mfma_f32_16x16x32_bf16(a[m], b[n], acc[m][n], 0, 0, 0);
        cur = (cur == 2) ? 0 : cur + 1;
    }
    const int rj = l4 * 4;
#pragma unroll
    for (int m = 0; m < 4; m++) {
#pragma unroll
        for (int j = 0; j < 4; j++) {
            int lr2 = wr * 64 + m * 16 + rj + j;
            if (m0 + lr2 < cnt) {
                int slot = slot_s[lr2];
                size_t rowoff = (size_t)slot * ID + n0 + wc * 64 + l15;
#pragma unroll
                for (int n = 0; n < 4; n++) {
                    float v = acc[m][n][j];
                    v = 0.5f * v * (1.f + erff(v * 0.70710678118654752f));  // exact gelu
                    hbuf[rowoff + n * 16] = f2bf(v);
                }
            }
        }
    }
}

// GEMM2: pout[slot] = gate[slot] * (h_gathered @ w2[e]^T). K=3072. bf16 partials.
__launch_bounds__(512, 2)
__global__ void k_gemm2(const unsigned short* __restrict__ hbuf, const unsigned short* __restrict__ w2b,
                        const int* __restrict__ lists, const int* __restrict__ counts,
                        const int2* __restrict__ table,
                        const float* __restrict__ gates, unsigned short* __restrict__ pout) {
    const int2 ent = table[xcd_swz(blockIdx.x)];
    const int e = ent.x;
    if (e < 0) return;
    const int m0 = ent.y;
    const int cnt = counts[e];
    const int n0 = blockIdx.y * BN;
    __shared__ __align__(16) unsigned short As[3 * ASZ];
    __shared__ __align__(16) unsigned short Bs[3 * BSZ];
    __shared__ int slot_s[BM];
    const int tid = threadIdx.x, lane = tid & 63, wid = tid >> 6;
    if (tid < BM) {
        int r = m0 + tid;
        slot_s[tid] = lists[e * NT + (r < cnt ? r : cnt - 1)];
    }
    __syncthreads();

    const int rsub = lane >> 2;
    const int keyS = (rsub & 3) ^ ((rsub >> 2) & 3);
    const int sw = ((lane & 3) ^ keyS) * 8;
    const unsigned short* gA[2];
#pragma unroll
    for (int i = 0; i < 2; i++) {
        int row = wid * 16 + rsub + 128 * i;
        gA[i] = hbuf + (size_t)slot_s[row] * ID + sw;
    }
    const unsigned short* gB = w2b + ((size_t)e * HD + n0 + wid * 16 + rsub) * ID + sw;
    auto stage = [&](int bf) {
#pragma unroll
        for (int i = 0; i < 2; i++) { gload16(gA[i], As + bf * ASZ + (wid + 8 * i) * 512); gA[i] += BK; }
        gload16(gB, Bs + bf * BSZ + wid * 512); gB += BK;
    };

    const int wr = wid >> 1, wc = wid & 1;
    const int l15 = lane & 15, l4 = lane >> 4;
    const int keyF = (l15 & 3) ^ ((l15 >> 2) & 3);
    const int aBase = (wr * 64 + l15) * BK;
    const int bBase = (wc * 64 + l15) * BK;
    const int cs = (l4 ^ keyF) * 8;

    f32x4 acc[4][4];
    f32x4 zero = {0.f, 0.f, 0.f, 0.f};
#pragma unroll
    for (int m = 0; m < 4; m++)
#pragma unroll
        for (int n = 0; n < 4; n++) acc[m][n] = zero;

    const int NK = ID / BK;      // 96
    stage(0); stage(1);
    int cur = 0, pf = 2;
    for (int kt = 0; kt < NK; ++kt) {
        if (kt + 1 < NK) asm volatile("s_waitcnt vmcnt(3)\ns_barrier" ::: "memory");
        else             asm volatile("s_waitcnt vmcnt(0)\ns_barrier" ::: "memory");
        if (kt + 2 < NK) { stage(pf); pf = (pf == 2) ? 0 : pf + 1; }
        const unsigned short* Ab = As + cur * ASZ;
        const unsigned short* Bb = Bs + cur * BSZ;
        bf16x8 a[4], b[4];
#pragma unroll
        for (int m = 0; m < 4; m++) a[m] = *(const bf16x8*)(Ab + aBase + m * 512 + cs);
#pragma unroll
        for (int n = 0; n < 4; n++) b[n] = *(const bf16x8*)(Bb + bBase + n * 512 + cs);
#pragma unroll
        for (int m = 0; m < 4; m++)
#pragma unroll
            for (int n = 0; n < 4; n++)
                acc[m][n] = __builtin_amdgcn_mfma_f32_16x16x32_bf16(a[m], b[n], acc[m][n], 0, 0, 0);
        cur = (cur == 2) ? 0 : cur + 1;
    }
    const int rj = l4 * 4;
#pragma unroll
    for (int m = 0; m < 4; m++) {
#pragma unroll
        for (int j = 0; j < 4; j++) {
            int lr2 = wr * 64 + m * 16 + rj + j;
            if (m0 + lr2 < cnt) {
                int slot = slot_s[lr2];
                float g = gates[slot];
                size_t rowoff = (size_t)slot * HD + n0 + wc * 64 + l15;
#pragma unroll
                for (int n = 0; n < 4; n++)
                    pout[rowoff + n * 16] = f2bf(g * acc[m][n][j]);
            }
        }
    }
}

// out[t] = pout[2t] + pout[2t+1] + bias   (pout is bf16)
__global__ void k_combine(const unsigned short* __restrict__ pout, const float* __restrict__ bias,
                          float4* __restrict__ out) {
    int idx = blockIdx.x * 256 + threadIdx.x;   // over NT*HD/4
    int t = idx / (HD / 4);
    int c = idx - t * (HD / 4);
    ushort4 a = ((const ushort4*)pout)[(size_t)t * (2 * HD / 4) + c];
    ushort4 b = ((const ushort4*)pout)[(size_t)t * (2 * HD / 4) + HD / 4 + c];
    float4 bb = ((const float4*)bias)[c];
    float4 r;
    r.x = bf2f(a.x) + bf2f(b.x) + bb.x;
    r.y = bf2f(a.y) + bf2f(b.y) + bb.y;
    r.z = bf2f(a.z) + bf2f(b.z) + bb.z;
    r.w = bf2f(a.w) + bf2f(b.w) + bb.w;
    out[idx] = r;
}

extern "C" void kernel_launch(void* const* d_in, const int* in_sizes, int n_in,
                              void* d_out, int out_size, void* d_ws, size_t ws_size,
                              hipStream_t stream) {
    const float* x    = (const float*)d_in[0];
    const float* rw   = (const float*)d_in[1];
    const float* w1   = (const float*)d_in[2];
    const float* w2   = (const float*)d_in[3];
    const float* bias = (const float*)d_in[4];
    float* out = (float*)d_out;

    char* ws = (char*)d_ws;
    size_t off = 0;
    auto alloc = [&](size_t bytes) -> char* {
        char* p = ws + off;
        off += (bytes + 255) & ~(size_t)255;
        return p;
    };
    int*            counts = (int*)alloc(NE * 4);
    int2*           table  = (int2*)alloc(MAXB * sizeof(int2));
    int*            lists  = (int*)alloc((size_t)NE * NT * 4);
    float*          gates  = (float*)alloc((size_t)NT * 2 * 4);
    uchar2*         choice = (uchar2*)alloc((size_t)NT * 2);
    unsigned short* xb     = (unsigned short*)alloc((size_t)NT * HD * 2);
    unsigned short* w1b    = (unsigned short*)alloc((size_t)NE * ID * HD * 2);
    unsigned short* w2b    = (unsigned short*)alloc((size_t)NE * HD * ID * 2);
    unsigned short* hbuf   = (unsigned short*)alloc((size_t)NT * 2 * ID * 2);
    unsigned short* pout   = (unsigned short*)alloc((size_t)NT * 2 * HD * 2);

    const int n4 = NE * ID * HD / 4;
    k_convertw<<<dim3((n4 + 255) / 256), dim3(256), 0, stream>>>(
        (const float4*)w1, (const float4*)w2, (ushort4*)w1b, (ushort4*)w2b, n4);
    k_router<<<dim3(NT / 32), dim3(256), 0, stream>>>(x, rw, (ushort4*)xb, gates, choice);
    k_scatter<<<dim3(NE), dim3(256), 0, stream>>>(choice, lists, counts);
    k_plan<<<dim3(1), dim3(256), 0, stream>>>(counts, table);
    k_gemm1<<<dim3(MAXB, ID / BN), dim3(512), 0, stream>>>(xb, w1b, lists, counts, table, hbuf);
    k_gemm2<<<dim3(MAXB, HD / BN), dim3(512), 0, stream>>>(hbuf, w2b, lists, counts, table, gates, pout);
    k_combine<<<dim3(NT * HD / 4 / 256), dim3(256), 0, stream>>>(pout, bias, (float4*)out);
}

// Round 7
// 309.669 us; speedup vs baseline: 2.3153x; 1.1022x over previous
//
#include <hip/hip_runtime.h>
#include <hip/hip_bf16.h>
#include <math.h>

#define NT 8192
#define HD 768
#define ID 3072
#define NE 8
#define BK 32
// gemm1: 128x128 tile, 4 waves, 3 blocks/CU. gemm2: 256x128, 8 waves.
#define MAXB1 136   // >= sum_e ceil(cnt_e/128); 136 = 8*17 (bijective XCD swizzle)
#define MAXB2 72    // >= sum_e ceil(cnt_e/256); 72 = 8*9
#define ASZ1 (128 * BK)
#define ASZ2 (256 * BK)
#define BSZ  (128 * BK)

typedef __bf16 bf16x8 __attribute__((ext_vector_type(8)));
typedef float f32x4 __attribute__((ext_vector_type(4)));

__device__ __forceinline__ unsigned short f2bf(float f) {
    union { float f; unsigned u; } v; v.f = f;
    unsigned r = v.u + 0x7FFFu + ((v.u >> 16) & 1u);   // RNE
    return (unsigned short)(r >> 16);
}
__device__ __forceinline__ float bf2f(unsigned short b) {
    union { unsigned u; float f; } v; v.u = ((unsigned)b) << 16;
    return v.f;
}
// tanh-form gelu; |delta vs exact erf-gelu| <= ~3e-4 (budget 1.95e-2)
__device__ __forceinline__ float gelu_t(float v) {
    float u = 0.7978845608028654f * (v + 0.044715f * v * v * v);
    float t = __expf(-2.0f * fabsf(u));
    float th = (1.0f - t) / (1.0f + t);
    return 0.5f * v * (1.0f + copysignf(th, u));
}

// global->LDS direct copy, 16B/lane. LDS dest = wave-uniform base + lane*16.
__device__ __forceinline__ void gload16(const void* g, void* l) {
    auto* lds = reinterpret_cast<__attribute__((address_space(3))) unsigned int*>(
        reinterpret_cast<uintptr_t>(l));
    auto* gp = reinterpret_cast<const __attribute__((address_space(1))) unsigned int*>(
        reinterpret_cast<uintptr_t>(g));
    __builtin_amdgcn_global_load_lds(gp, lds, 16, 0, 0);
}

__global__ void k_convertw(const float4* __restrict__ w1, const float4* __restrict__ w2,
                           ushort4* __restrict__ w1b, ushort4* __restrict__ w2b, int n) {
    int i = blockIdx.x * 256 + threadIdx.x;
    if (i >= n) return;
    float4 a = w1[i]; float4 b = w2[i];
    ushort4 ra, rb;
    ra.x = f2bf(a.x); ra.y = f2bf(a.y); ra.z = f2bf(a.z); ra.w = f2bf(a.w);
    rb.x = f2bf(b.x); rb.y = f2bf(b.y); rb.z = f2bf(b.z); rb.w = f2bf(b.w);
    w1b[i] = ra; w2b[i] = rb;
}

// Router phase 1: exact fp32 logits/softmax/top-2 (ties -> lowest index). No atomics.
__global__ void k_router(const float* __restrict__ x, const float* __restrict__ rw,
                         ushort4* __restrict__ xb4, float* __restrict__ gates,
                         uchar2* __restrict__ choice) {
    __shared__ float rws[NE * HD];
    const int tid = threadIdx.x;
    for (int i = tid; i < NE * HD / 4; i += 256)
        ((float4*)rws)[i] = ((const float4*)rw)[i];
    __syncthreads();
    const int wid = tid >> 6, lane = tid & 63;
    const float4* rws4 = (const float4*)rws;
    for (int it = 0; it < 8; ++it) {
        const int t = blockIdx.x * 32 + wid * 8 + it;
        const float4* xp4 = (const float4*)(x + (size_t)t * HD);
        float acc[NE];
#pragma unroll
        for (int e = 0; e < NE; e++) acc[e] = 0.f;
#pragma unroll
        for (int j = 0; j < HD / 256; j++) {
            float4 v = xp4[lane + 64 * j];
            ushort4 o;
            o.x = f2bf(v.x); o.y = f2bf(v.y); o.z = f2bf(v.z); o.w = f2bf(v.w);
            xb4[(size_t)t * (HD / 4) + lane + 64 * j] = o;
#pragma unroll
            for (int e = 0; e < NE; e++) {
                float4 w = rws4[e * (HD / 4) + lane + 64 * j];
                acc[e] += v.x * w.x + v.y * w.y + v.z * w.z + v.w * w.w;
            }
        }
#pragma unroll
        for (int e = 0; e < NE; e++)
            for (int off = 32; off; off >>= 1) acc[e] += __shfl_xor(acc[e], off);
        if (lane == 0) {
            float mx = acc[0];
#pragma unroll
            for (int e = 1; e < NE; e++) mx = fmaxf(mx, acc[e]);
            float p[NE], s = 0.f;
#pragma unroll
            for (int e = 0; e < NE; e++) { p[e] = __expf(acc[e] - mx); s += p[e]; }
            float inv = 1.f / s;
            int i1 = 0; float b1 = p[0];
#pragma unroll
            for (int e = 1; e < NE; e++) if (p[e] > b1) { b1 = p[e]; i1 = e; }
            int i2 = (i1 == 0) ? 1 : 0; float b2 = p[i2];
#pragma unroll
            for (int e = 0; e < NE; e++) if (e != i1 && p[e] > b2) { b2 = p[e]; i2 = e; }
            choice[t].x = (unsigned char)i1;
            choice[t].y = (unsigned char)i2;
            gates[2 * t] = b1 * inv;
            gates[2 * t + 1] = b2 * inv;
        }
    }
}

// Router phase 2: one block per expert; ballot/prefix-scan compaction. No atomics.
__global__ void k_scatter(const uchar2* __restrict__ choice,
                          int* __restrict__ lists, int* __restrict__ counts) {
    const int e = blockIdx.x;
    const int tid = threadIdx.x, wid = tid >> 6, lane = tid & 63;
    __shared__ int wtot[4];
    __shared__ int running;
    if (tid == 0) running = 0;
    __syncthreads();
    for (int t0 = 0; t0 < NT; t0 += 256) {
        const int t = t0 + tid;
        uchar2 c = choice[t];
        bool m1 = (c.x == e), m2 = (c.y == e);
        bool m = m1 || m2;
        int slot = m1 ? 2 * t : 2 * t + 1;
        unsigned long long mask = __ballot(m);
        int off = __popcll(mask & ((1ULL << lane) - 1ULL));
        if (lane == 0) wtot[wid] = __popcll(mask);
        __syncthreads();
        int base = running;
        for (int w = 0; w < wid; w++) base += wtot[w];
        if (m) lists[e * NT + base + off] = slot;
        __syncthreads();
        if (tid == 0) running += wtot[0] + wtot[1] + wtot[2] + wtot[3];
        __syncthreads();
    }
    if (tid == 0) counts[e] = running;
}

// Compact block tables: table1 = 128-row m-tiles, table2 = 256-row m-tiles.
__global__ void k_plan(const int* __restrict__ counts,
                       int2* __restrict__ table1, int2* __restrict__ table2) {
    __shared__ int s1[NE + 1], s2[NE + 1];
    const int tid = threadIdx.x;
    if (tid == 0) {
        int a = 0, b = 0;
        for (int e = 0; e < NE; e++) {
            s1[e] = a; a += (counts[e] + 127) >> 7;
            s2[e] = b; b += (counts[e] + 255) >> 8;
        }
        s1[NE] = a; s2[NE] = b;
    }
    __syncthreads();
    for (int b = tid; b < MAXB1; b += 256) {
        int e = -1, m0 = 0;
#pragma unroll
        for (int q = 0; q < NE; q++)
            if (b >= s1[q] && b < s1[q + 1]) { e = q; m0 = (b - s1[q]) << 7; }
        table1[b].x = e; table1[b].y = m0;
    }
    for (int b = tid; b < MAXB2; b += 256) {
        int e = -1, m0 = 0;
#pragma unroll
        for (int q = 0; q < NE; q++)
            if (b >= s2[q] && b < s2[q + 1]) { e = q; m0 = (b - s2[q]) << 8; }
        table2[b].x = e; table2[b].y = m0;
    }
}

// LDS layout (both GEMMs): rows of 64 B (4 x 16 B chunks); chunk c of row r
// stored at c ^ key(r), key(r) = (r>>1)&3. Bank groups (r&1)*4 + key(r) are
// exactly 2-to-1 over any 16 consecutive rows -> ds_read_b128 is 2-way (free).
// Staging stays coalesced (4-lane groups read a permuted 64 B of one row).
// XCD swizzle: bijective since gridDim.x % 8 == 0.

// GEMM1: h[slot] = gelu(x_gathered @ w1[e]^T). 128x128, 4 waves, 3 blocks/CU.
__launch_bounds__(256, 3)
__global__ void k_gemm1(const unsigned short* __restrict__ xb, const unsigned short* __restrict__ w1b,
                        const int* __restrict__ lists, const int* __restrict__ counts,
                        const int2* __restrict__ table,
                        unsigned short* __restrict__ hbuf) {
    const int2 ent = table[(blockIdx.x & 7) * (MAXB1 >> 3) + (blockIdx.x >> 3)];
    const int e = ent.x;
    if (e < 0) return;
    const int m0 = ent.y;
    const int cnt = counts[e];
    const int n0 = blockIdx.y * 128;
    __shared__ __align__(16) unsigned short As[3 * ASZ1];
    __shared__ __align__(16) unsigned short Bs[3 * BSZ];
    __shared__ int slot_s[128];
    const int tid = threadIdx.x, lane = tid & 63, wid = tid >> 6;
    if (tid < 128) {
        int r = m0 + tid;
        slot_s[tid] = lists[e * NT + (r < cnt ? r : cnt - 1)];
    }
    __syncthreads();

    const int rsub = lane >> 2;                         // 0..15: row within window
    const int sw = (((lane & 3) ^ ((rsub >> 1) & 3)) * 8);
    const int row0 = wid * 16 + rsub;                   // windows wid and wid+4
    const unsigned short* gA0 = xb + (size_t)(slot_s[row0] >> 1) * HD + sw;
    const unsigned short* gA1 = xb + (size_t)(slot_s[row0 + 64] >> 1) * HD + sw;
    const unsigned short* gB0 = w1b + ((size_t)e * ID + n0 + row0) * HD + sw;
    const unsigned short* gB1 = gB0 + (size_t)64 * HD;
    auto stage = [&](int bf) {
        gload16(gA0, As + bf * ASZ1 + wid * 512);       gA0 += BK;
        gload16(gA1, As + bf * ASZ1 + (wid + 4) * 512); gA1 += BK;
        gload16(gB0, Bs + bf * BSZ + wid * 512);        gB0 += BK;
        gload16(gB1, Bs + bf * BSZ + (wid + 4) * 512);  gB1 += BK;
    };

    const int wr = wid >> 1, wc = wid & 1;
    const int l15 = lane & 15, l4 = lane >> 4;
    const int aBase = (wr * 64 + l15) * BK;
    const int bBase = (wc * 64 + l15) * BK;
    const int cs = (l4 ^ ((l15 >> 1) & 3)) * 8;

    f32x4 acc[4][4];
    f32x4 zero = {0.f, 0.f, 0.f, 0.f};
#pragma unroll
    for (int m = 0; m < 4; m++)
#pragma unroll
        for (int n = 0; n < 4; n++) acc[m][n] = zero;

    const int NK = HD / BK;      // 24
    stage(0); stage(1);
    int cur = 0, pf = 2;
    for (int kt = 0; kt < NK; ++kt) {
        if (kt + 1 < NK) asm volatile("s_waitcnt vmcnt(4)\ns_barrier" ::: "memory");
        else             asm volatile("s_waitcnt vmcnt(0)\ns_barrier" ::: "memory");
        if (kt + 2 < NK) { stage(pf); pf = (pf == 2) ? 0 : pf + 1; }
        const unsigned short* Ab = As + cur * ASZ1;
        const unsigned short* Bb = Bs + cur * BSZ;
        bf16x8 a[4], b[4];
#pragma unroll
        for (int m = 0; m < 4; m++) a[m] = *(const bf16x8*)(Ab + aBase + m * 512 + cs);
#pragma unroll
        for (int n = 0; n < 4; n++) b[n] = *(const bf16x8*)(Bb + bBase + n * 512 + cs);
#pragma unroll
        for (int m = 0; m < 4; m++)
#pragma unroll
            for (int n = 0; n < 4; n++)
                acc[m][n] = __builtin_amdgcn_mfma_f32_16x16x32_bf16(a[m], b[n], acc[m][n], 0, 0, 0);
        cur = (cur == 2) ? 0 : cur + 1;
    }
    const int rj = l4 * 4;
#pragma unroll
    for (int m = 0; m < 4; m++) {
#pragma unroll
        for (int j = 0; j < 4; j++) {
            int lr2 = wr * 64 + m * 16 + rj + j;
            if (m0 + lr2 < cnt) {
                int slot = slot_s[lr2];
                size_t rowoff = (size_t)slot * ID + n0 + wc * 64 + l15;
#pragma unroll
                for (int n = 0; n < 4; n++)
                    hbuf[rowoff + n * 16] = f2bf(gelu_t(acc[m][n][j]));
            }
        }
    }
}

// GEMM2: pout[slot] = gate[slot] * (h_gathered @ w2[e]^T). 256x128, 8 waves, K=3072.
__launch_bounds__(512, 2)
__global__ void k_gemm2(const unsigned short* __restrict__ hbuf, const unsigned short* __restrict__ w2b,
                        const int* __restrict__ lists, const int* __restrict__ counts,
                        const int2* __restrict__ table,
                        const float* __restrict__ gates, unsigned short* __restrict__ pout) {
    const int2 ent = table[(blockIdx.x & 7) * (MAXB2 >> 3) + (blockIdx.x >> 3)];
    const int e = ent.x;
    if (e < 0) return;
    const int m0 = ent.y;
    const int cnt = counts[e];
    const int n0 = blockIdx.y * 128;
    __shared__ __align__(16) unsigned short As[3 * ASZ2];
    __shared__ __align__(16) unsigned short Bs[3 * BSZ];
    __shared__ int slot_s[256];
    const int tid = threadIdx.x, lane = tid & 63, wid = tid >> 6;
    if (tid < 256) {
        int r = m0 + tid;
        slot_s[tid] = lists[e * NT + (r < cnt ? r : cnt - 1)];
    }
    __syncthreads();

    const int rsub = lane >> 2;
    const int sw = (((lane & 3) ^ ((rsub >> 1) & 3)) * 8);
    const unsigned short* gA[2];
#pragma unroll
    for (int i = 0; i < 2; i++) {
        int row = wid * 16 + rsub + 128 * i;
        gA[i] = hbuf + (size_t)slot_s[row] * ID + sw;
    }
    const unsigned short* gB = w2b + ((size_t)e * HD + n0 + wid * 16 + rsub) * ID + sw;
    auto stage = [&](int bf) {
#pragma unroll
        for (int i = 0; i < 2; i++) { gload16(gA[i], As + bf * ASZ2 + (wid + 8 * i) * 512); gA[i] += BK; }
        gload16(gB, Bs + bf * BSZ + wid * 512); gB += BK;
    };

    const int wr = wid >> 1, wc = wid & 1;
    const int l15 = lane & 15, l4 = lane >> 4;
    const int aBase = (wr * 64 + l15) * BK;
    const int bBase = (wc * 64 + l15) * BK;
    const int cs = (l4 ^ ((l15 >> 1) & 3)) * 8;

    f32x4 acc[4][4];
    f32x4 zero = {0.f, 0.f, 0.f, 0.f};
#pragma unroll
    for (int m = 0; m < 4; m++)
#pragma unroll
        for (int n = 0; n < 4; n++) acc[m][n] = zero;

    const int NK = ID / BK;      // 96
    stage(0); stage(1);
    int cur = 0, pf = 2;
    for (int kt = 0; kt < NK; ++kt) {
        if (kt + 1 < NK) asm volatile("s_waitcnt vmcnt(3)\ns_barrier" ::: "memory");
        else             asm volatile("s_waitcnt vmcnt(0)\ns_barrier" ::: "memory");
        if (kt + 2 < NK) { stage(pf); pf = (pf == 2) ? 0 : pf + 1; }
        const unsigned short* Ab = As + cur * ASZ2;
        const unsigned short* Bb = Bs + cur * BSZ;
        bf16x8 a[4], b[4];
#pragma unroll
        for (int m = 0; m < 4; m++) a[m] = *(const bf16x8*)(Ab + aBase + m * 512 + cs);
#pragma unroll
        for (int n = 0; n < 4; n++) b[n] = *(const bf16x8*)(Bb + bBase + n * 512 + cs);
#pragma unroll
        for (int m = 0; m < 4; m++)
#pragma unroll
            for (int n = 0; n < 4; n++)
                acc[m][n] = __builtin_amdgcn_mfma_f32_16x16x32_bf16(a[m], b[n], acc[m][n], 0, 0, 0);
        cur = (cur == 2) ? 0 : cur + 1;
    }
    const int rj = l4 * 4;
#pragma unroll
    for (int m = 0; m < 4; m++) {
#pragma unroll
        for (int j = 0; j < 4; j++) {
            int lr2 = wr * 64 + m * 16 + rj + j;
            if (m0 + lr2 < cnt) {
                int slot = slot_s[lr2];
                float g = gates[slot];
                size_t rowoff = (size_t)slot * HD + n0 + wc * 64 + l15;
#pragma unroll
                for (int n = 0; n < 4; n++)
                    pout[rowoff + n * 16] = f2bf(g * acc[m][n][j]);
            }
        }
    }
}

// out[t] = pout[2t] + pout[2t+1] + bias   (pout is bf16)
__global__ void k_combine(const unsigned short* __restrict__ pout, const float* __restrict__ bias,
                          float4* __restrict__ out) {
    int idx = blockIdx.x * 256 + threadIdx.x;   // over NT*HD/4
    int t = idx / (HD / 4);
    int c = idx - t * (HD / 4);
    ushort4 a = ((const ushort4*)pout)[(size_t)t * (2 * HD / 4) + c];
    ushort4 b = ((const ushort4*)pout)[(size_t)t * (2 * HD / 4) + HD / 4 + c];
    float4 bb = ((const float4*)bias)[c];
    float4 r;
    r.x = bf2f(a.x) + bf2f(b.x) + bb.x;
    r.y = bf2f(a.y) + bf2f(b.y) + bb.y;
    r.z = bf2f(a.z) + bf2f(b.z) + bb.z;
    r.w = bf2f(a.w) + bf2f(b.w) + bb.w;
    out[idx] = r;
}

extern "C" void kernel_launch(void* const* d_in, const int* in_sizes, int n_in,
                              void* d_out, int out_size, void* d_ws, size_t ws_size,
                              hipStream_t stream) {
    const float* x    = (const float*)d_in[0];
    const float* rw   = (const float*)d_in[1];
    const float* w1   = (const float*)d_in[2];
    const float* w2   = (const float*)d_in[3];
    const float* bias = (const float*)d_in[4];
    float* out = (float*)d_out;

    char* ws = (char*)d_ws;
    size_t off = 0;
    auto alloc = [&](size_t bytes) -> char* {
        char* p = ws + off;
        off += (bytes + 255) & ~(size_t)255;
        return p;
    };
    int*            counts = (int*)alloc(NE * 4);
    int2*           table1 = (int2*)alloc(MAXB1 * sizeof(int2));
    int2*           table2 = (int2*)alloc(MAXB2 * sizeof(int2));
    int*            lists  = (int*)alloc((size_t)NE * NT * 4);
    float*          gates  = (float*)alloc((size_t)NT * 2 * 4);
    uchar2*         choice = (uchar2*)alloc((size_t)NT * 2);
    unsigned short* xb     = (unsigned short*)alloc((size_t)NT * HD * 2);
    unsigned short* w1b    = (unsigned short*)alloc((size_t)NE * ID * HD * 2);
    unsigned short* w2b    = (unsigned short*)alloc((size_t)NE * HD * ID * 2);
    unsigned short* hbuf   = (unsigned short*)alloc((size_t)NT * 2 * ID * 2);
    unsigned short* pout   = (unsigned short*)alloc((size_t)NT * 2 * HD * 2);

    const int n4 = NE * ID * HD / 4;
    k_convertw<<<dim3((n4 + 255) / 256), dim3(256), 0, stream>>>(
        (const float4*)w1, (const float4*)w2, (ushort4*)w1b, (ushort4*)w2b, n4);
    k_router<<<dim3(NT / 32), dim3(256), 0, stream>>>(x, rw, (ushort4*)xb, gates, choice);
    k_scatter<<<dim3(NE), dim3(256), 0, stream>>>(choice, lists, counts);
    k_plan<<<dim3(1), dim3(256), 0, stream>>>(counts, table1, table2);
    k_gemm1<<<dim3(MAXB1, ID / 128), dim3(256), 0, stream>>>(xb, w1b, lists, counts, table1, hbuf);
    k_gemm2<<<dim3(MAXB2, HD / 128), dim3(512), 0, stream>>>(hbuf, w2b, lists, counts, table2, gates, pout);
    k_combine<<<dim3(NT * HD / 4 / 256), dim3(256), 0, stream>>>(pout, bias, (float4*)out);
}

// Round 8
// 293.521 us; speedup vs baseline: 2.4427x; 1.0550x over previous
//
#include <hip/hip_runtime.h>
#include <hip/hip_bf16.h>
#include <math.h>

#define NT 8192
#define HD 768
#define ID 3072
#define NE 8
#define BK 32
#define MAXB1 136   // >= sum_e ceil(cnt_e/128); 136 = 8*17 (bijective XCD swizzle)
#define MAXB2 72    // >= sum_e ceil(cnt_e/256); 72 = 8*9
#define ASZ1 (128 * BK)
#define ASZ2 (256 * BK)
#define BSZ  (128 * BK)
#define RT_BLOCKS (NT / 32)                 // 256 router blocks
#define CONV_BLOCKS (NE * ID * HD / 4 / 256) // 18432 convert blocks

typedef __bf16 bf16x8 __attribute__((ext_vector_type(8)));
typedef float f32x4 __attribute__((ext_vector_type(4)));

__device__ __forceinline__ unsigned short f2bf(float f) {
    union { float f; unsigned u; } v; v.f = f;
    unsigned r = v.u + 0x7FFFu + ((v.u >> 16) & 1u);   // RNE
    return (unsigned short)(r >> 16);
}
__device__ __forceinline__ float bf2f(unsigned short b) {
    union { unsigned u; float f; } v; v.u = ((unsigned)b) << 16;
    return v.f;
}
// gelu(tanh form) == v * sigmoid(2u), 2u = c1*v + c2*v^3. 1 exp + 1 rcp.
__device__ __forceinline__ float gelu_s(float v) {
    float z = v * (1.5957691216057308f + 0.07135481283687945f * v * v);
    float e = __expf(-z);
    return v * __builtin_amdgcn_rcpf(1.0f + e);
}

// global->LDS direct copy, 16B/lane. LDS dest = wave-uniform base + lane*16.
__device__ __forceinline__ void gload16(const void* g, void* l) {
    auto* lds = reinterpret_cast<__attribute__((address_space(3))) unsigned int*>(
        reinterpret_cast<uintptr_t>(l));
    auto* gp = reinterpret_cast<const __attribute__((address_space(1))) unsigned int*>(
        reinterpret_cast<uintptr_t>(g));
    __builtin_amdgcn_global_load_lds(gp, lds, 16, 0, 0);
}

// Fused front: blocks [0,RT_BLOCKS) = router (dispatched first, hides under
// convert); blocks [RT_BLOCKS, RT_BLOCKS+CONV_BLOCKS) = fp32->bf16 weight convert.
__global__ void k_front(const float* __restrict__ x, const float* __restrict__ rw,
                        const float4* __restrict__ w1, const float4* __restrict__ w2,
                        ushort4* __restrict__ w1b, ushort4* __restrict__ w2b,
                        ushort4* __restrict__ xb4, float* __restrict__ gates,
                        uchar2* __restrict__ choice) {
    __shared__ float rws[NE * HD];
    const int tid = threadIdx.x;
    if (blockIdx.x >= RT_BLOCKS) {
        int i = (blockIdx.x - RT_BLOCKS) * 256 + tid;
        float4 a = w1[i]; float4 b = w2[i];
        ushort4 ra, rb;
        ra.x = f2bf(a.x); ra.y = f2bf(a.y); ra.z = f2bf(a.z); ra.w = f2bf(a.w);
        rb.x = f2bf(b.x); rb.y = f2bf(b.y); rb.z = f2bf(b.z); rb.w = f2bf(b.w);
        w1b[i] = ra; w2b[i] = rb;
        return;
    }
    // ---- router: exact fp32 logits/softmax/top-2 (ties -> lowest index) ----
    for (int i = tid; i < NE * HD / 4; i += 256)
        ((float4*)rws)[i] = ((const float4*)rw)[i];
    __syncthreads();
    const int wid = tid >> 6, lane = tid & 63;
    const float4* rws4 = (const float4*)rws;
    for (int it = 0; it < 8; ++it) {
        const int t = blockIdx.x * 32 + wid * 8 + it;
        const float4* xp4 = (const float4*)(x + (size_t)t * HD);
        float acc[NE];
#pragma unroll
        for (int e = 0; e < NE; e++) acc[e] = 0.f;
#pragma unroll
        for (int j = 0; j < HD / 256; j++) {
            float4 v = xp4[lane + 64 * j];
            ushort4 o;
            o.x = f2bf(v.x); o.y = f2bf(v.y); o.z = f2bf(v.z); o.w = f2bf(v.w);
            xb4[(size_t)t * (HD / 4) + lane + 64 * j] = o;
#pragma unroll
            for (int e = 0; e < NE; e++) {
                float4 w = rws4[e * (HD / 4) + lane + 64 * j];
                acc[e] += v.x * w.x + v.y * w.y + v.z * w.z + v.w * w.w;
            }
        }
#pragma unroll
        for (int e = 0; e < NE; e++)
            for (int off = 32; off; off >>= 1) acc[e] += __shfl_xor(acc[e], off);
        if (lane == 0) {
            float mx = acc[0];
#pragma unroll
            for (int e = 1; e < NE; e++) mx = fmaxf(mx, acc[e]);
            float p[NE], s = 0.f;
#pragma unroll
            for (int e = 0; e < NE; e++) { p[e] = __expf(acc[e] - mx); s += p[e]; }
            float inv = 1.f / s;
            int i1 = 0; float b1 = p[0];
#pragma unroll
            for (int e = 1; e < NE; e++) if (p[e] > b1) { b1 = p[e]; i1 = e; }
            int i2 = (i1 == 0) ? 1 : 0; float b2 = p[i2];
#pragma unroll
            for (int e = 0; e < NE; e++) if (e != i1 && p[e] > b2) { b2 = p[e]; i2 = e; }
            choice[t].x = (unsigned char)i1;
            choice[t].y = (unsigned char)i2;
            gates[2 * t] = b1 * inv;
            gates[2 * t + 1] = b2 * inv;
        }
    }
}

// Router phase 2: one block per expert; ballot/prefix-scan compaction. No atomics.
__global__ void k_scatter(const uchar2* __restrict__ choice,
                          int* __restrict__ lists, int* __restrict__ counts) {
    const int e = blockIdx.x;
    const int tid = threadIdx.x, wid = tid >> 6, lane = tid & 63;
    __shared__ int wtot[4];
    __shared__ int running;
    if (tid == 0) running = 0;
    __syncthreads();
    for (int t0 = 0; t0 < NT; t0 += 256) {
        const int t = t0 + tid;
        uchar2 c = choice[t];
        bool m1 = (c.x == e), m2 = (c.y == e);
        bool m = m1 || m2;
        int slot = m1 ? 2 * t : 2 * t + 1;
        unsigned long long mask = __ballot(m);
        int off = __popcll(mask & ((1ULL << lane) - 1ULL));
        if (lane == 0) wtot[wid] = __popcll(mask);
        __syncthreads();
        int base = running;
        for (int w = 0; w < wid; w++) base += wtot[w];
        if (m) lists[e * NT + base + off] = slot;
        __syncthreads();
        if (tid == 0) running += wtot[0] + wtot[1] + wtot[2] + wtot[3];
        __syncthreads();
    }
    if (tid == 0) counts[e] = running;
}

// LDS layout (both GEMMs): rows of 64 B (4 x 16 B chunks); chunk c of row r at
// c ^ ((r>>1)&3) -> ds_read_b128 2-way (free), staging coalesced via source perm.
// MFMA operand swap: acc[m][n] = mfma(b[n], a[m], acc) gives D^T fragments:
// lane&15 = M (token row), (lane>>4)*4+j = N offset -> j is 4 consecutive cols
// -> packed uint2 epilogue stores. Block's (e,m0) derived inline from counts.

// GEMM1: h[slot] = gelu(x_gathered @ w1[e]^T). 128x128, 4 waves, 3 blocks/CU.
__launch_bounds__(256, 3)
__global__ void k_gemm1(const unsigned short* __restrict__ xb, const unsigned short* __restrict__ w1b,
                        const int* __restrict__ lists, const int* __restrict__ counts,
                        unsigned short* __restrict__ hbuf) {
    const int bsw = (blockIdx.x & 7) * (MAXB1 >> 3) + (blockIdx.x >> 3);
    int e = -1, m0 = 0;
    {
        int s = 0;
#pragma unroll
        for (int q = 0; q < NE; q++) {
            int nb = (counts[q] + 127) >> 7;
            if (bsw >= s && bsw < s + nb) { e = q; m0 = (bsw - s) << 7; }
            s += nb;
        }
    }
    if (e < 0) return;
    const int cnt = counts[e];
    const int n0 = blockIdx.y * 128;
    __shared__ __align__(16) unsigned short As[3 * ASZ1];
    __shared__ __align__(16) unsigned short Bs[3 * BSZ];
    __shared__ int slot_s[128];
    const int tid = threadIdx.x, lane = tid & 63, wid = tid >> 6;
    if (tid < 128) {
        int r = m0 + tid;
        slot_s[tid] = lists[e * NT + (r < cnt ? r : cnt - 1)];
    }
    __syncthreads();

    const int rsub = lane >> 2;
    const int sw = (((lane & 3) ^ ((rsub >> 1) & 3)) * 8);
    const int row0 = wid * 16 + rsub;
    const unsigned short* gA0 = xb + (size_t)(slot_s[row0] >> 1) * HD + sw;
    const unsigned short* gA1 = xb + (size_t)(slot_s[row0 + 64] >> 1) * HD + sw;
    const unsigned short* gB0 = w1b + ((size_t)e * ID + n0 + row0) * HD + sw;
    const unsigned short* gB1 = gB0 + (size_t)64 * HD;
    auto stage = [&](int bf) {
        gload16(gA0, As + bf * ASZ1 + wid * 512);       gA0 += BK;
        gload16(gA1, As + bf * ASZ1 + (wid + 4) * 512); gA1 += BK;
        gload16(gB0, Bs + bf * BSZ + wid * 512);        gB0 += BK;
        gload16(gB1, Bs + bf * BSZ + (wid + 4) * 512);  gB1 += BK;
    };

    const int wr = wid >> 1, wc = wid & 1;
    const int l15 = lane & 15, l4 = lane >> 4;
    const int aBase = (wr * 64 + l15) * BK;
    const int bBase = (wc * 64 + l15) * BK;
    const int cs = (l4 ^ ((l15 >> 1) & 3)) * 8;

    f32x4 acc[4][4];
    f32x4 zero = {0.f, 0.f, 0.f, 0.f};
#pragma unroll
    for (int m = 0; m < 4; m++)
#pragma unroll
        for (int n = 0; n < 4; n++) acc[m][n] = zero;

    const int NK = HD / BK;      // 24
    stage(0); stage(1);
    int cur = 0, pf = 2;
    for (int kt = 0; kt < NK; ++kt) {
        if (kt + 1 < NK) asm volatile("s_waitcnt vmcnt(4)\ns_barrier" ::: "memory");
        else             asm volatile("s_waitcnt vmcnt(0)\ns_barrier" ::: "memory");
        if (kt + 2 < NK) { stage(pf); pf = (pf == 2) ? 0 : pf + 1; }
        const unsigned short* Ab = As + cur * ASZ1;
        const unsigned short* Bb = Bs + cur * BSZ;
        bf16x8 a[4], b[4];
#pragma unroll
        for (int m = 0; m < 4; m++) a[m] = *(const bf16x8*)(Ab + aBase + m * 512 + cs);
#pragma unroll
        for (int n = 0; n < 4; n++) b[n] = *(const bf16x8*)(Bb + bBase + n * 512 + cs);
#pragma unroll
        for (int m = 0; m < 4; m++)
#pragma unroll
            for (int n = 0; n < 4; n++)
                acc[m][n] = __builtin_amdgcn_mfma_f32_16x16x32_bf16(b[n], a[m], acc[m][n], 0, 0, 0);
        cur = (cur == 2) ? 0 : cur + 1;
    }
    const int rj = l4 * 4;
#pragma unroll
    for (int m = 0; m < 4; m++) {
        int lr2 = wr * 64 + m * 16 + l15;
        if (m0 + lr2 < cnt) {
            int slot = slot_s[lr2];
            unsigned short* hp = hbuf + (size_t)slot * ID + n0 + wc * 64 + rj;
#pragma unroll
            for (int n = 0; n < 4; n++) {
                float g0 = gelu_s(acc[m][n][0]);
                float g1 = gelu_s(acc[m][n][1]);
                float g2 = gelu_s(acc[m][n][2]);
                float g3 = gelu_s(acc[m][n][3]);
                uint2 pk;
                pk.x = ((unsigned)f2bf(g1) << 16) | f2bf(g0);
                pk.y = ((unsigned)f2bf(g3) << 16) | f2bf(g2);
                *(uint2*)(hp + n * 16) = pk;
            }
        }
    }
}

// GEMM2: pout[slot] = gate[slot] * (h_gathered @ w2[e]^T). 256x128, 8 waves, K=3072.
__launch_bounds__(512, 2)
__global__ void k_gemm2(const unsigned short* __restrict__ hbuf, const unsigned short* __restrict__ w2b,
                        const int* __restrict__ lists, const int* __restrict__ counts,
                        const float* __restrict__ gates, unsigned short* __restrict__ pout) {
    const int bsw = (blockIdx.x & 7) * (MAXB2 >> 3) + (blockIdx.x >> 3);
    int e = -1, m0 = 0;
    {
        int s = 0;
#pragma unroll
        for (int q = 0; q < NE; q++) {
            int nb = (counts[q] + 255) >> 8;
            if (bsw >= s && bsw < s + nb) { e = q; m0 = (bsw - s) << 8; }
            s += nb;
        }
    }
    if (e < 0) return;
    const int cnt = counts[e];
    const int n0 = blockIdx.y * 128;
    __shared__ __align__(16) unsigned short As[3 * ASZ2];
    __shared__ __align__(16) unsigned short Bs[3 * BSZ];
    __shared__ int slot_s[256];
    const int tid = threadIdx.x, lane = tid & 63, wid = tid >> 6;
    if (tid < 256) {
        int r = m0 + tid;
        slot_s[tid] = lists[e * NT + (r < cnt ? r : cnt - 1)];
    }
    __syncthreads();

    const int rsub = lane >> 2;
    const int sw = (((lane & 3) ^ ((rsub >> 1) & 3)) * 8);
    const unsigned short* gA[2];
#pragma unroll
    for (int i = 0; i < 2; i++) {
        int row = wid * 16 + rsub + 128 * i;
        gA[i] = hbuf + (size_t)slot_s[row] * ID + sw;
    }
    const unsigned short* gB = w2b + ((size_t)e * HD + n0 + wid * 16 + rsub) * ID + sw;
    auto stage = [&](int bf) {
#pragma unroll
        for (int i = 0; i < 2; i++) { gload16(gA[i], As + bf * ASZ2 + (wid + 8 * i) * 512); gA[i] += BK; }
        gload16(gB, Bs + bf * BSZ + wid * 512); gB += BK;
    };

    const int wr = wid >> 1, wc = wid & 1;
    const int l15 = lane & 15, l4 = lane >> 4;
    const int aBase = (wr * 64 + l15) * BK;
    const int bBase = (wc * 64 + l15) * BK;
    const int cs = (l4 ^ ((l15 >> 1) & 3)) * 8;

    f32x4 acc[4][4];
    f32x4 zero = {0.f, 0.f, 0.f, 0.f};
#pragma unroll
    for (int m = 0; m < 4; m++)
#pragma unroll
        for (int n = 0; n < 4; n++) acc[m][n] = zero;

    const int NK = ID / BK;      // 96
    stage(0); stage(1);
    int cur = 0, pf = 2;
    for (int kt = 0; kt < NK; ++kt) {
        if (kt + 1 < NK) asm volatile("s_waitcnt vmcnt(3)\ns_barrier" ::: "memory");
        else             asm volatile("s_waitcnt vmcnt(0)\ns_barrier" ::: "memory");
        if (kt + 2 < NK) { stage(pf); pf = (pf == 2) ? 0 : pf + 1; }
        const unsigned short* Ab = As + cur * ASZ2;
        const unsigned short* Bb = Bs + cur * BSZ;
        bf16x8 a[4], b[4];
#pragma unroll
        for (int m = 0; m < 4; m++) a[m] = *(const bf16x8*)(Ab + aBase + m * 512 + cs);
#pragma unroll
        for (int n = 0; n < 4; n++) b[n] = *(const bf16x8*)(Bb + bBase + n * 512 + cs);
#pragma unroll
        for (int m = 0; m < 4; m++)
#pragma unroll
            for (int n = 0; n < 4; n++)
                acc[m][n] = __builtin_amdgcn_mfma_f32_16x16x32_bf16(b[n], a[m], acc[m][n], 0, 0, 0);
        cur = (cur == 2) ? 0 : cur + 1;
    }
    const int rj = l4 * 4;
#pragma unroll
    for (int m = 0; m < 4; m++) {
        int lr2 = wr * 64 + m * 16 + l15;
        if (m0 + lr2 < cnt) {
            int slot = slot_s[lr2];
            float g = gates[slot];
            unsigned short* pp = pout + (size_t)slot * HD + n0 + wc * 64 + rj;
#pragma unroll
            for (int n = 0; n < 4; n++) {
                float g0 = g * acc[m][n][0];
                float g1 = g * acc[m][n][1];
                float g2 = g * acc[m][n][2];
                float g3 = g * acc[m][n][3];
                uint2 pk;
                pk.x = ((unsigned)f2bf(g1) << 16) | f2bf(g0);
                pk.y = ((unsigned)f2bf(g3) << 16) | f2bf(g2);
                *(uint2*)(pp + n * 16) = pk;
            }
        }
    }
}

// out[t] = pout[2t] + pout[2t+1] + bias   (pout is bf16)
__global__ void k_combine(const unsigned short* __restrict__ pout, const float* __restrict__ bias,
                          float4* __restrict__ out) {
    int idx = blockIdx.x * 256 + threadIdx.x;   // over NT*HD/4
    int t = idx / (HD / 4);
    int c = idx - t * (HD / 4);
    ushort4 a = ((const ushort4*)pout)[(size_t)t * (2 * HD / 4) + c];
    ushort4 b = ((const ushort4*)pout)[(size_t)t * (2 * HD / 4) + HD / 4 + c];
    float4 bb = ((const float4*)bias)[c];
    float4 r;
    r.x = bf2f(a.x) + bf2f(b.x) + bb.x;
    r.y = bf2f(a.y) + bf2f(b.y) + bb.y;
    r.z = bf2f(a.z) + bf2f(b.z) + bb.z;
    r.w = bf2f(a.w) + bf2f(b.w) + bb.w;
    out[idx] = r;
}

extern "C" void kernel_launch(void* const* d_in, const int* in_sizes, int n_in,
                              void* d_out, int out_size, void* d_ws, size_t ws_size,
                              hipStream_t stream) {
    const float* x    = (const float*)d_in[0];
    const float* rw   = (const float*)d_in[1];
    const float* w1   = (const float*)d_in[2];
    const float* w2   = (const float*)d_in[3];
    const float* bias = (const float*)d_in[4];
    float* out = (float*)d_out;

    char* ws = (char*)d_ws;
    size_t off = 0;
    auto alloc = [&](size_t bytes) -> char* {
        char* p = ws + off;
        off += (bytes + 255) & ~(size_t)255;
        return p;
    };
    int*            counts = (int*)alloc(NE * 4);
    int*            lists  = (int*)alloc((size_t)NE * NT * 4);
    float*          gates  = (float*)alloc((size_t)NT * 2 * 4);
    uchar2*         choice = (uchar2*)alloc((size_t)NT * 2);
    unsigned short* xb     = (unsigned short*)alloc((size_t)NT * HD * 2);
    unsigned short* w1b    = (unsigned short*)alloc((size_t)NE * ID * HD * 2);
    unsigned short* w2b    = (unsigned short*)alloc((size_t)NE * HD * ID * 2);
    unsigned short* hbuf   = (unsigned short*)alloc((size_t)NT * 2 * ID * 2);
    unsigned short* pout   = (unsigned short*)alloc((size_t)NT * 2 * HD * 2);

    k_front<<<dim3(RT_BLOCKS + CONV_BLOCKS), dim3(256), 0, stream>>>(
        x, rw, (const float4*)w1, (const float4*)w2,
        (ushort4*)w1b, (ushort4*)w2b, (ushort4*)xb, gates, choice);
    k_scatter<<<dim3(NE), dim3(256), 0, stream>>>(choice, lists, counts);
    k_gemm1<<<dim3(MAXB1, ID / 128), dim3(256), 0, stream>>>(xb, w1b, lists, counts, hbuf);
    k_gemm2<<<dim3(MAXB2, HD / 128), dim3(512), 0, stream>>>(hbuf, w2b, lists, counts, gates, pout);
    k_combine<<<dim3(NT * HD / 4 / 256), dim3(256), 0, stream>>>(pout, bias, (float4*)out);
}

// Round 9
// 286.710 us; speedup vs baseline: 2.5007x; 1.0238x over previous
//
#include <hip/hip_runtime.h>
#include <hip/hip_bf16.h>
#include <math.h>

#define NT 8192
#define HD 768
#define ID 3072
#define NE 8
#define BK 32
#define MAXB1 136   // >= sum_e ceil(cnt_e/128); 136 = 8*17 (bijective XCD swizzle)
#define MAXB2 72    // >= sum_e ceil(cnt_e/256); 72 = 8*9
#define ASZ1 (128 * BK)
#define BSZ1 (256 * BK)
#define ASZ2 (256 * BK)
#define BSZ2 (128 * BK)
#define RT_BLOCKS (NT / 32)                 // 256 router blocks
#define CONV_BLOCKS (NE * ID * HD / 4 / 256) // 18432 convert blocks

typedef __bf16 bf16x8 __attribute__((ext_vector_type(8)));
typedef float f32x4 __attribute__((ext_vector_type(4)));

__device__ __forceinline__ unsigned short f2bf(float f) {
    union { float f; unsigned u; } v; v.f = f;
    unsigned r = v.u + 0x7FFFu + ((v.u >> 16) & 1u);   // RNE
    return (unsigned short)(r >> 16);
}
__device__ __forceinline__ float bf2f(unsigned short b) {
    union { unsigned u; float f; } v; v.u = ((unsigned)b) << 16;
    return v.f;
}
// gelu(tanh form) == v * sigmoid(2u), 2u = c1*v + c2*v^3. 1 exp + 1 rcp.
__device__ __forceinline__ float gelu_s(float v) {
    float z = v * (1.5957691216057308f + 0.07135481283687945f * v * v);
    float e = __expf(-z);
    return v * __builtin_amdgcn_rcpf(1.0f + e);
}

// global->LDS direct copy, 16B/lane. LDS dest = wave-uniform base + lane*16.
__device__ __forceinline__ void gload16(const void* g, void* l) {
    auto* lds = reinterpret_cast<__attribute__((address_space(3))) unsigned int*>(
        reinterpret_cast<uintptr_t>(l));
    auto* gp = reinterpret_cast<const __attribute__((address_space(1))) unsigned int*>(
        reinterpret_cast<uintptr_t>(g));
    __builtin_amdgcn_global_load_lds(gp, lds, 16, 0, 0);
}

// Fused front: blocks [0,RT_BLOCKS) = router; rest = fp32->bf16 weight convert.
__global__ void k_front(const float* __restrict__ x, const float* __restrict__ rw,
                        const float4* __restrict__ w1, const float4* __restrict__ w2,
                        ushort4* __restrict__ w1b, ushort4* __restrict__ w2b,
                        ushort4* __restrict__ xb4, float* __restrict__ gates,
                        uchar2* __restrict__ choice) {
    __shared__ float rws[NE * HD];
    const int tid = threadIdx.x;
    if (blockIdx.x >= RT_BLOCKS) {
        int i = (blockIdx.x - RT_BLOCKS) * 256 + tid;
        float4 a = w1[i]; float4 b = w2[i];
        ushort4 ra, rb;
        ra.x = f2bf(a.x); ra.y = f2bf(a.y); ra.z = f2bf(a.z); ra.w = f2bf(a.w);
        rb.x = f2bf(b.x); rb.y = f2bf(b.y); rb.z = f2bf(b.z); rb.w = f2bf(b.w);
        w1b[i] = ra; w2b[i] = rb;
        return;
    }
    for (int i = tid; i < NE * HD / 4; i += 256)
        ((float4*)rws)[i] = ((const float4*)rw)[i];
    __syncthreads();
    const int wid = tid >> 6, lane = tid & 63;
    const float4* rws4 = (const float4*)rws;
    for (int it = 0; it < 8; ++it) {
        const int t = blockIdx.x * 32 + wid * 8 + it;
        const float4* xp4 = (const float4*)(x + (size_t)t * HD);
        float acc[NE];
#pragma unroll
        for (int e = 0; e < NE; e++) acc[e] = 0.f;
#pragma unroll
        for (int j = 0; j < HD / 256; j++) {
            float4 v = xp4[lane + 64 * j];
            ushort4 o;
            o.x = f2bf(v.x); o.y = f2bf(v.y); o.z = f2bf(v.z); o.w = f2bf(v.w);
            xb4[(size_t)t * (HD / 4) + lane + 64 * j] = o;
#pragma unroll
            for (int e = 0; e < NE; e++) {
                float4 w = rws4[e * (HD / 4) + lane + 64 * j];
                acc[e] += v.x * w.x + v.y * w.y + v.z * w.z + v.w * w.w;
            }
        }
#pragma unroll
        for (int e = 0; e < NE; e++)
            for (int off = 32; off; off >>= 1) acc[e] += __shfl_xor(acc[e], off);
        if (lane == 0) {
            float mx = acc[0];
#pragma unroll
            for (int e = 1; e < NE; e++) mx = fmaxf(mx, acc[e]);
            float p[NE], s = 0.f;
#pragma unroll
            for (int e = 0; e < NE; e++) { p[e] = __expf(acc[e] - mx); s += p[e]; }
            float inv = 1.f / s;
            int i1 = 0; float b1 = p[0];
#pragma unroll
            for (int e = 1; e < NE; e++) if (p[e] > b1) { b1 = p[e]; i1 = e; }
            int i2 = (i1 == 0) ? 1 : 0; float b2 = p[i2];
#pragma unroll
            for (int e = 0; e < NE; e++) if (e != i1 && p[e] > b2) { b2 = p[e]; i2 = e; }
            choice[t].x = (unsigned char)i1;
            choice[t].y = (unsigned char)i2;
            gates[2 * t] = b1 * inv;
            gates[2 * t + 1] = b2 * inv;
        }
    }
}

// Router phase 2: one block per expert; ballot/prefix-scan compaction. No atomics.
__global__ void k_scatter(const uchar2* __restrict__ choice,
                          int* __restrict__ lists, int* __restrict__ counts) {
    const int e = blockIdx.x;
    const int tid = threadIdx.x, wid = tid >> 6, lane = tid & 63;
    __shared__ int wtot[4];
    __shared__ int running;
    if (tid == 0) running = 0;
    __syncthreads();
    for (int t0 = 0; t0 < NT; t0 += 256) {
        const int t = t0 + tid;
        uchar2 c = choice[t];
        bool m1 = (c.x == e), m2 = (c.y == e);
        bool m = m1 || m2;
        int slot = m1 ? 2 * t : 2 * t + 1;
        unsigned long long mask = __ballot(m);
        int off = __popcll(mask & ((1ULL << lane) - 1ULL));
        if (lane == 0) wtot[wid] = __popcll(mask);
        __syncthreads();
        int base = running;
        for (int w = 0; w < wid; w++) base += wtot[w];
        if (m) lists[e * NT + base + off] = slot;
        __syncthreads();
        if (tid == 0) running += wtot[0] + wtot[1] + wtot[2] + wtot[3];
        __syncthreads();
    }
    if (tid == 0) counts[e] = running;
}

// LDS layout (both GEMMs): rows of 64 B (4 x 16 B chunks); chunk c of row r at
// c ^ ((r>>1)&3) -> ds_read_b128 2-way (free), staging coalesced via source perm.
// MFMA operand swap (b,a) -> D^T fragments -> packed uint2 epilogue stores.

// GEMM1: h[slot] = gelu(x_gathered @ w1[e]^T). 128x256 tile, 4 waves
// (wave tile 64x128, acc 4x8), BK=32, 3 buffers (72 KB -> 2 blocks/CU),
// depth-2 pipeline: 6 gload16/wave/stage, wait vmcnt(6).
__launch_bounds__(256, 2)
__global__ void k_gemm1(const unsigned short* __restrict__ xb, const unsigned short* __restrict__ w1b,
                        const int* __restrict__ lists, const int* __restrict__ counts,
                        unsigned short* __restrict__ hbuf) {
    const int bsw = (blockIdx.x & 7) * (MAXB1 >> 3) + (blockIdx.x >> 3);
    int e = -1, m0 = 0;
    {
        int s = 0;
#pragma unroll
        for (int q = 0; q < NE; q++) {
            int nb = (counts[q] + 127) >> 7;
            if (bsw >= s && bsw < s + nb) { e = q; m0 = (bsw - s) << 7; }
            s += nb;
        }
    }
    if (e < 0) return;
    const int cnt = counts[e];
    const int n0 = blockIdx.y * 256;
    __shared__ __align__(16) unsigned short As[3 * ASZ1];
    __shared__ __align__(16) unsigned short Bs[3 * BSZ1];
    __shared__ int slot_s[128];
    const int tid = threadIdx.x, lane = tid & 63, wid = tid >> 6;
    if (tid < 128) {
        int r = m0 + tid;
        slot_s[tid] = lists[e * NT + (r < cnt ? r : cnt - 1)];
    }
    __syncthreads();

    const int rsub = lane >> 2;
    const int sw = (((lane & 3) ^ ((rsub >> 1) & 3)) * 8);
    const int row0 = wid * 16 + rsub;
    const unsigned short* gA0 = xb + (size_t)(slot_s[row0] >> 1) * HD + sw;
    const unsigned short* gA1 = xb + (size_t)(slot_s[row0 + 64] >> 1) * HD + sw;
    const unsigned short* gB[4];
#pragma unroll
    for (int i = 0; i < 4; i++)
        gB[i] = w1b + ((size_t)e * ID + n0 + row0 + 64 * i) * HD + sw;
    auto stage = [&](int bf) {
        gload16(gA0, As + bf * ASZ1 + wid * 512);       gA0 += BK;
        gload16(gA1, As + bf * ASZ1 + (wid + 4) * 512); gA1 += BK;
#pragma unroll
        for (int i = 0; i < 4; i++) {
            gload16(gB[i], Bs + bf * BSZ1 + (wid + 4 * i) * 512); gB[i] += BK;
        }
    };

    const int wr = wid >> 1, wc = wid & 1;
    const int l15 = lane & 15, l4 = lane >> 4;
    const int aBase = (wr * 64 + l15) * BK;
    const int bBase = (wc * 128 + l15) * BK;
    const int cs = (l4 ^ ((l15 >> 1) & 3)) * 8;

    f32x4 acc[4][8];
    f32x4 zero = {0.f, 0.f, 0.f, 0.f};
#pragma unroll
    for (int m = 0; m < 4; m++)
#pragma unroll
        for (int n = 0; n < 8; n++) acc[m][n] = zero;

    const int NK = HD / BK;      // 24
    stage(0); stage(1);
    int cur = 0, pf = 2;
    for (int kt = 0; kt < NK; ++kt) {
        if (kt + 1 < NK) asm volatile("s_waitcnt vmcnt(6)\ns_barrier" ::: "memory");
        else             asm volatile("s_waitcnt vmcnt(0)\ns_barrier" ::: "memory");
        if (kt + 2 < NK) { stage(pf); pf = (pf == 2) ? 0 : pf + 1; }
        const unsigned short* Ab = As + cur * ASZ1;
        const unsigned short* Bb = Bs + cur * BSZ1;
        bf16x8 a[4], b[8];
#pragma unroll
        for (int m = 0; m < 4; m++) a[m] = *(const bf16x8*)(Ab + aBase + m * 512 + cs);
#pragma unroll
        for (int n = 0; n < 8; n++) b[n] = *(const bf16x8*)(Bb + bBase + n * 512 + cs);
#pragma unroll
        for (int m = 0; m < 4; m++)
#pragma unroll
            for (int n = 0; n < 8; n++)
                acc[m][n] = __builtin_amdgcn_mfma_f32_16x16x32_bf16(b[n], a[m], acc[m][n], 0, 0, 0);
        cur = (cur == 2) ? 0 : cur + 1;
    }
    const int rj = l4 * 4;
#pragma unroll
    for (int m = 0; m < 4; m++) {
        int lr2 = wr * 64 + m * 16 + l15;
        if (m0 + lr2 < cnt) {
            int slot = slot_s[lr2];
            unsigned short* hp = hbuf + (size_t)slot * ID + n0 + wc * 128 + rj;
#pragma unroll
            for (int n = 0; n < 8; n++) {
                float g0 = gelu_s(acc[m][n][0]);
                float g1 = gelu_s(acc[m][n][1]);
                float g2 = gelu_s(acc[m][n][2]);
                float g3 = gelu_s(acc[m][n][3]);
                uint2 pk;
                pk.x = ((unsigned)f2bf(g1) << 16) | f2bf(g0);
                pk.y = ((unsigned)f2bf(g3) << 16) | f2bf(g2);
                *(uint2*)(hp + n * 16) = pk;
            }
        }
    }
}

// GEMM2: pout[slot] = gate[slot] * (h_gathered @ w2[e]^T). 256x128, 8 waves, K=3072.
__launch_bounds__(512, 2)
__global__ void k_gemm2(const unsigned short* __restrict__ hbuf, const unsigned short* __restrict__ w2b,
                        const int* __restrict__ lists, const int* __restrict__ counts,
                        const float* __restrict__ gates, unsigned short* __restrict__ pout) {
    const int bsw = (blockIdx.x & 7) * (MAXB2 >> 3) + (blockIdx.x >> 3);
    int e = -1, m0 = 0;
    {
        int s = 0;
#pragma unroll
        for (int q = 0; q < NE; q++) {
            int nb = (counts[q] + 255) >> 8;
            if (bsw >= s && bsw < s + nb) { e = q; m0 = (bsw - s) << 8; }
            s += nb;
        }
    }
    if (e < 0) return;
    const int cnt = counts[e];
    const int n0 = blockIdx.y * 128;
    __shared__ __align__(16) unsigned short As[3 * ASZ2];
    __shared__ __align__(16) unsigned short Bs[3 * BSZ2];
    __shared__ int slot_s[256];
    const int tid = threadIdx.x, lane = tid & 63, wid = tid >> 6;
    if (tid < 256) {
        int r = m0 + tid;
        slot_s[tid] = lists[e * NT + (r < cnt ? r : cnt - 1)];
    }
    __syncthreads();

    const int rsub = lane >> 2;
    const int sw = (((lane & 3) ^ ((rsub >> 1) & 3)) * 8);
    const unsigned short* gA[2];
#pragma unroll
    for (int i = 0; i < 2; i++) {
        int row = wid * 16 + rsub + 128 * i;
        gA[i] = hbuf + (size_t)slot_s[row] * ID + sw;
    }
    const unsigned short* gB = w2b + ((size_t)e * HD + n0 + wid * 16 + rsub) * ID + sw;
    auto stage = [&](int bf) {
#pragma unroll
        for (int i = 0; i < 2; i++) { gload16(gA[i], As + bf * ASZ2 + (wid + 8 * i) * 512); gA[i] += BK; }
        gload16(gB, Bs + bf * BSZ2 + wid * 512); gB += BK;
    };

    const int wr = wid >> 1, wc = wid & 1;
    const int l15 = lane & 15, l4 = lane >> 4;
    const int aBase = (wr * 64 + l15) * BK;
    const int bBase = (wc * 64 + l15) * BK;
    const int cs = (l4 ^ ((l15 >> 1) & 3)) * 8;

    f32x4 acc[4][4];
    f32x4 zero = {0.f, 0.f, 0.f, 0.f};
#pragma unroll
    for (int m = 0; m < 4; m++)
#pragma unroll
        for (int n = 0; n < 4; n++) acc[m][n] = zero;

    const int NK = ID / BK;      // 96
    stage(0); stage(1);
    int cur = 0, pf = 2;
    for (int kt = 0; kt < NK; ++kt) {
        if (kt + 1 < NK) asm volatile("s_waitcnt vmcnt(3)\ns_barrier" ::: "memory");
        else             asm volatile("s_waitcnt vmcnt(0)\ns_barrier" ::: "memory");
        if (kt + 2 < NK) { stage(pf); pf = (pf == 2) ? 0 : pf + 1; }
        const unsigned short* Ab = As + cur * ASZ2;
        const unsigned short* Bb = Bs + cur * BSZ2;
        bf16x8 a[4], b[4];
#pragma unroll
        for (int m = 0; m < 4; m++) a[m] = *(const bf16x8*)(Ab + aBase + m * 512 + cs);
#pragma unroll
        for (int n = 0; n < 4; n++) b[n] = *(const bf16x8*)(Bb + bBase + n * 512 + cs);
#pragma unroll
        for (int m = 0; m < 4; m++)
#pragma unroll
            for (int n = 0; n < 4; n++)
                acc[m][n] = __builtin_amdgcn_mfma_f32_16x16x32_bf16(b[n], a[m], acc[m][n], 0, 0, 0);
        cur = (cur == 2) ? 0 : cur + 1;
    }
    const int rj = l4 * 4;
#pragma unroll
    for (int m = 0; m < 4; m++) {
        int lr2 = wr * 64 + m * 16 + l15;
        if (m0 + lr2 < cnt) {
            int slot = slot_s[lr2];
            float g = gates[slot];
            unsigned short* pp = pout + (size_t)slot * HD + n0 + wc * 64 + rj;
#pragma unroll
            for (int n = 0; n < 4; n++) {
                float g0 = g * acc[m][n][0];
                float g1 = g * acc[m][n][1];
                float g2 = g * acc[m][n][2];
                float g3 = g * acc[m][n][3];
                uint2 pk;
                pk.x = ((unsigned)f2bf(g1) << 16) | f2bf(g0);
                pk.y = ((unsigned)f2bf(g3) << 16) | f2bf(g2);
                *(uint2*)(pp + n * 16) = pk;
            }
        }
    }
}

// out[t] = pout[2t] + pout[2t+1] + bias   (pout is bf16)
__global__ void k_combine(const unsigned short* __restrict__ pout, const float* __restrict__ bias,
                          float4* __restrict__ out) {
    int idx = blockIdx.x * 256 + threadIdx.x;   // over NT*HD/4
    int t = idx / (HD / 4);
    int c = idx - t * (HD / 4);
    ushort4 a = ((const ushort4*)pout)[(size_t)t * (2 * HD / 4) + c];
    ushort4 b = ((const ushort4*)pout)[(size_t)t * (2 * HD / 4) + HD / 4 + c];
    float4 bb = ((const float4*)bias)[c];
    float4 r;
    r.x = bf2f(a.x) + bf2f(b.x) + bb.x;
    r.y = bf2f(a.y) + bf2f(b.y) + bb.y;
    r.z = bf2f(a.z) + bf2f(b.z) + bb.z;
    r.w = bf2f(a.w) + bf2f(b.w) + bb.w;
    out[idx] = r;
}

extern "C" void kernel_launch(void* const* d_in, const int* in_sizes, int n_in,
                              void* d_out, int out_size, void* d_ws, size_t ws_size,
                              hipStream_t stream) {
    const float* x    = (const float*)d_in[0];
    const float* rw   = (const float*)d_in[1];
    const float* w1   = (const float*)d_in[2];
    const float* w2   = (const float*)d_in[3];
    const float* bias = (const float*)d_in[4];
    float* out = (float*)d_out;

    char* ws = (char*)d_ws;
    size_t off = 0;
    auto alloc = [&](size_t bytes) -> char* {
        char* p = ws + off;
        off += (bytes + 255) & ~(size_t)255;
        return p;
    };
    int*            counts = (int*)alloc(NE * 4);
    int*            lists  = (int*)alloc((size_t)NE * NT * 4);
    float*          gates  = (float*)alloc((size_t)NT * 2 * 4);
    uchar2*         choice = (uchar2*)alloc((size_t)NT * 2);
    unsigned short* xb     = (unsigned short*)alloc((size_t)NT * HD * 2);
    unsigned short* w1b    = (unsigned short*)alloc((size_t)NE * ID * HD * 2);
    unsigned short* w2b    = (unsigned short*)alloc((size_t)NE * HD * ID * 2);
    unsigned short* hbuf   = (unsigned short*)alloc((size_t)NT * 2 * ID * 2);
    unsigned short* pout   = (unsigned short*)alloc((size_t)NT * 2 * HD * 2);

    k_front<<<dim3(RT_BLOCKS + CONV_BLOCKS), dim3(256), 0, stream>>>(
        x, rw, (const float4*)w1, (const float4*)w2,
        (ushort4*)w1b, (ushort4*)w2b, (ushort4*)xb, gates, choice);
    k_scatter<<<dim3(NE), dim3(256), 0, stream>>>(choice, lists, counts);
    k_gemm1<<<dim3(MAXB1, ID / 256), dim3(256), 0, stream>>>(xb, w1b, lists, counts, hbuf);
    k_gemm2<<<dim3(MAXB2, HD / 128), dim3(512), 0, stream>>>(hbuf, w2b, lists, counts, gates, pout);
    k_combine<<<dim3(NT * HD / 4 / 256), dim3(256), 0, stream>>>(pout, bias, (float4*)out);
}